// Round 1
// baseline (3850.549 us; speedup 1.0000x reference)
//
#include <hip/hip_runtime.h>

// GraphSAGE 2-layer, fp32 correctness-first baseline.
// Layer1: agg1 = scatter-mean(x over ei1) [100000,128]; h = relu([agg1|x]@ [Wl1;Wr1] + b1)
// Layer2: p = h @ Wl2 (project BEFORE aggregation: mean commutes with linear);
//         out = scatter-mean(p over ei2) + h[:50000] @ Wr2 + b2
//
// ws layout (floats):
//   agg1  [100000*128] = 12.8M
//   cnt1  [100000] (int)
//   h     [100000*256] = 25.6M
//   p     [100000*64]  = 6.4M
//   aggp  [50000*64]   = 3.2M
//   cnt2  [50000] (int)
// total ~48.2M floats = 193 MB

#define NSRC 200000
#define NMID 100000
#define NTGT 50000
#define NE1  1600000
#define NE2  800000
#define DIN  128
#define DHID 256
#define DOUT 64

#define BM 64
#define BN 64
#define KT 16

__global__ __launch_bounds__(256) void scatter1_kernel(
    const float* __restrict__ x, const int* __restrict__ ei,
    float* __restrict__ agg, int* __restrict__ cnt)
{
    long long gid = (long long)blockIdx.x * blockDim.x + threadIdx.x;
    int e = (int)(gid >> 5);
    int sub = (int)(gid & 31);
    if (e >= NE1) return;
    int src = ei[e];
    int tgt = ei[NE1 + e];
    float4 v = *(const float4*)(x + (long long)src * DIN + sub * 4);
    float* dst = agg + (long long)tgt * DIN + sub * 4;
    unsafeAtomicAdd(dst + 0, v.x);
    unsafeAtomicAdd(dst + 1, v.y);
    unsafeAtomicAdd(dst + 2, v.z);
    unsafeAtomicAdd(dst + 3, v.w);
    if (sub == 0) atomicAdd(cnt + tgt, 1);
}

__global__ __launch_bounds__(256) void normalize1_kernel(
    float* __restrict__ agg, const int* __restrict__ cnt)
{
    int gid = blockIdx.x * blockDim.x + threadIdx.x;
    if (gid >= NMID * (DIN / 4)) return;
    int row = gid >> 5;  // 32 float4 per row
    float inv = 1.0f / fmaxf((float)cnt[row], 1.0f);
    float4* p = (float4*)agg + gid;
    float4 v = *p;
    v.x *= inv; v.y *= inv; v.z *= inv; v.w *= inv;
    *p = v;
}

// h = relu([aggn | x] @ [Wl1 ; Wr1] + b1)   M=NMID, K=256, N=256
__global__ __launch_bounds__(256) void gemm1_kernel(
    const float* __restrict__ aggn, const float* __restrict__ x,
    const float* __restrict__ Wl, const float* __restrict__ Wr,
    const float* __restrict__ bias, float* __restrict__ h)
{
    __shared__ float As[KT][BM + 4];
    __shared__ float Bs[KT][BN + 4];
    int bm = blockIdx.x * BM;
    int bn = blockIdx.y * BN;
    int tid = threadIdx.x;
    int tx = tid & 15, ty = tid >> 4;
    int lr = tid >> 2;          // A loader: row 0..63
    int lk = (tid & 3) * 4;     // A loader: k offset 0,4,8,12
    int lbk = tid >> 4;         // B loader: k 0..15
    int lbn = (tid & 15) * 4;   // B loader: n offset
    float acc[4][4] = {};
    for (int k0 = 0; k0 < 2 * DIN; k0 += KT) {
        int grow = bm + lr;
        int gk = k0 + lk;
        float4 av = {0.f, 0.f, 0.f, 0.f};
        if (grow < NMID) {
            const float* Asrc = (gk < DIN) ? (aggn + (long long)grow * DIN + gk)
                                           : (x + (long long)grow * DIN + (gk - DIN));
            av = *(const float4*)Asrc;
        }
        As[lk + 0][lr] = av.x; As[lk + 1][lr] = av.y;
        As[lk + 2][lr] = av.z; As[lk + 3][lr] = av.w;
        int gbk = k0 + lbk;
        const float* Bsrc = (gbk < DIN) ? (Wl + (long long)gbk * DHID)
                                        : (Wr + (long long)(gbk - DIN) * DHID);
        *(float4*)&Bs[lbk][lbn] = *(const float4*)(Bsrc + bn + lbn);
        __syncthreads();
        #pragma unroll
        for (int kk = 0; kk < KT; ++kk) {
            float4 a = *(float4*)&As[kk][ty * 4];
            float4 b = *(float4*)&Bs[kk][tx * 4];
            float aa[4] = {a.x, a.y, a.z, a.w};
            float bb[4] = {b.x, b.y, b.z, b.w};
            #pragma unroll
            for (int i = 0; i < 4; ++i)
                #pragma unroll
                for (int j = 0; j < 4; ++j)
                    acc[i][j] += aa[i] * bb[j];
        }
        __syncthreads();
    }
    #pragma unroll
    for (int i = 0; i < 4; ++i) {
        int row = bm + ty * 4 + i;
        if (row >= NMID) continue;
        #pragma unroll
        for (int j = 0; j < 4; ++j) {
            int col = bn + tx * 4 + j;
            float v = acc[i][j] + bias[col];
            h[(long long)row * DHID + col] = fmaxf(v, 0.0f);
        }
    }
}

// p = h @ Wl2   M=NMID, K=256, N=64
__global__ __launch_bounds__(256) void gemm2_kernel(
    const float* __restrict__ h, const float* __restrict__ W,
    float* __restrict__ p)
{
    __shared__ float As[KT][BM + 4];
    __shared__ float Bs[KT][BN + 4];
    int bm = blockIdx.x * BM;
    int tid = threadIdx.x;
    int tx = tid & 15, ty = tid >> 4;
    int lr = tid >> 2;
    int lk = (tid & 3) * 4;
    int lbk = tid >> 4;
    int lbn = (tid & 15) * 4;
    float acc[4][4] = {};
    for (int k0 = 0; k0 < DHID; k0 += KT) {
        int grow = bm + lr;
        int gk = k0 + lk;
        float4 av = {0.f, 0.f, 0.f, 0.f};
        if (grow < NMID) av = *(const float4*)(h + (long long)grow * DHID + gk);
        As[lk + 0][lr] = av.x; As[lk + 1][lr] = av.y;
        As[lk + 2][lr] = av.z; As[lk + 3][lr] = av.w;
        int gbk = k0 + lbk;
        *(float4*)&Bs[lbk][lbn] = *(const float4*)(W + (long long)gbk * DOUT + lbn);
        __syncthreads();
        #pragma unroll
        for (int kk = 0; kk < KT; ++kk) {
            float4 a = *(float4*)&As[kk][ty * 4];
            float4 b = *(float4*)&Bs[kk][tx * 4];
            float aa[4] = {a.x, a.y, a.z, a.w};
            float bb[4] = {b.x, b.y, b.z, b.w};
            #pragma unroll
            for (int i = 0; i < 4; ++i)
                #pragma unroll
                for (int j = 0; j < 4; ++j)
                    acc[i][j] += aa[i] * bb[j];
        }
        __syncthreads();
    }
    #pragma unroll
    for (int i = 0; i < 4; ++i) {
        int row = bm + ty * 4 + i;
        if (row >= NMID) continue;
        #pragma unroll
        for (int j = 0; j < 4; ++j) {
            int col = tx * 4 + j;
            p[(long long)row * DOUT + col] = acc[i][j];
        }
    }
}

__global__ __launch_bounds__(256) void scatter2_kernel(
    const float* __restrict__ p, const int* __restrict__ ei,
    float* __restrict__ aggp, int* __restrict__ cnt)
{
    long long gid = (long long)blockIdx.x * blockDim.x + threadIdx.x;
    int e = (int)(gid >> 4);
    int sub = (int)(gid & 15);
    if (e >= NE2) return;
    int src = ei[e];
    int tgt = ei[NE2 + e];
    float4 v = *(const float4*)(p + (long long)src * DOUT + sub * 4);
    float* dst = aggp + (long long)tgt * DOUT + sub * 4;
    unsafeAtomicAdd(dst + 0, v.x);
    unsafeAtomicAdd(dst + 1, v.y);
    unsafeAtomicAdd(dst + 2, v.z);
    unsafeAtomicAdd(dst + 3, v.w);
    if (sub == 0) atomicAdd(cnt + tgt, 1);
}

// out = aggp/cnt2 + h[:NTGT] @ Wr2 + b2   M=NTGT, K=256, N=64
__global__ __launch_bounds__(256) void final_kernel(
    const float* __restrict__ h, const float* __restrict__ W,
    const float* __restrict__ bias, const float* __restrict__ aggp,
    const int* __restrict__ cnt, float* __restrict__ out)
{
    __shared__ float As[KT][BM + 4];
    __shared__ float Bs[KT][BN + 4];
    int bm = blockIdx.x * BM;
    int tid = threadIdx.x;
    int tx = tid & 15, ty = tid >> 4;
    int lr = tid >> 2;
    int lk = (tid & 3) * 4;
    int lbk = tid >> 4;
    int lbn = (tid & 15) * 4;
    float acc[4][4] = {};
    for (int k0 = 0; k0 < DHID; k0 += KT) {
        int grow = bm + lr;
        int gk = k0 + lk;
        float4 av = {0.f, 0.f, 0.f, 0.f};
        if (grow < NTGT) av = *(const float4*)(h + (long long)grow * DHID + gk);
        As[lk + 0][lr] = av.x; As[lk + 1][lr] = av.y;
        As[lk + 2][lr] = av.z; As[lk + 3][lr] = av.w;
        int gbk = k0 + lbk;
        *(float4*)&Bs[lbk][lbn] = *(const float4*)(W + (long long)gbk * DOUT + lbn);
        __syncthreads();
        #pragma unroll
        for (int kk = 0; kk < KT; ++kk) {
            float4 a = *(float4*)&As[kk][ty * 4];
            float4 b = *(float4*)&Bs[kk][tx * 4];
            float aa[4] = {a.x, a.y, a.z, a.w};
            float bb[4] = {b.x, b.y, b.z, b.w};
            #pragma unroll
            for (int i = 0; i < 4; ++i)
                #pragma unroll
                for (int j = 0; j < 4; ++j)
                    acc[i][j] += aa[i] * bb[j];
        }
        __syncthreads();
    }
    #pragma unroll
    for (int i = 0; i < 4; ++i) {
        int row = bm + ty * 4 + i;
        if (row >= NTGT) continue;
        float inv = 1.0f / fmaxf((float)cnt[row], 1.0f);
        #pragma unroll
        for (int j = 0; j < 4; ++j) {
            int col = tx * 4 + j;
            out[(long long)row * DOUT + col] =
                acc[i][j] + bias[col] + aggp[(long long)row * DOUT + col] * inv;
        }
    }
}

extern "C" void kernel_launch(void* const* d_in, const int* in_sizes, int n_in,
                              void* d_out, int out_size, void* d_ws, size_t ws_size,
                              hipStream_t stream) {
    const float* x   = (const float*)d_in[0];
    const int*   ei1 = (const int*)d_in[1];
    const int*   ei2 = (const int*)d_in[2];
    const float* Wl1 = (const float*)d_in[3];
    const float* Wr1 = (const float*)d_in[4];
    const float* b1  = (const float*)d_in[5];
    const float* Wl2 = (const float*)d_in[6];
    const float* Wr2 = (const float*)d_in[7];
    const float* b2  = (const float*)d_in[8];
    float* out = (float*)d_out;

    float* agg1 = (float*)d_ws;
    int*   cnt1 = (int*)(agg1 + (size_t)NMID * DIN);
    float* h    = (float*)(cnt1 + NMID);
    float* p    = h + (size_t)NMID * DHID;
    float* aggp = p + (size_t)NMID * DOUT;
    int*   cnt2 = (int*)(aggp + (size_t)NTGT * DOUT);

    hipMemsetAsync(agg1, 0, (size_t)NMID * DIN * 4, stream);
    hipMemsetAsync(cnt1, 0, (size_t)NMID * 4, stream);
    hipMemsetAsync(aggp, 0, (size_t)NTGT * DOUT * 4, stream);
    hipMemsetAsync(cnt2, 0, (size_t)NTGT * 4, stream);

    {   // scatter layer 1: E1 edges x 32 lanes (4 floats each)
        long long threads = (long long)NE1 * 32;
        int blocks = (int)((threads + 255) / 256);
        scatter1_kernel<<<blocks, 256, 0, stream>>>(x, ei1, agg1, cnt1);
    }
    {   // normalize agg1 by counts
        int threads = NMID * (DIN / 4);
        normalize1_kernel<<<(threads + 255) / 256, 256, 0, stream>>>(agg1, cnt1);
    }
    {   // h = relu([agg1|x] @ [Wl1;Wr1] + b1)
        dim3 grid((NMID + BM - 1) / BM, DHID / BN);
        gemm1_kernel<<<grid, 256, 0, stream>>>(agg1, x, Wl1, Wr1, b1, h);
    }
    {   // p = h @ Wl2
        dim3 grid((NMID + BM - 1) / BM, 1);
        gemm2_kernel<<<grid, 256, 0, stream>>>(h, Wl2, p);
    }
    {   // scatter layer 2: E2 edges x 16 lanes
        long long threads = (long long)NE2 * 16;
        int blocks = (int)((threads + 255) / 256);
        scatter2_kernel<<<blocks, 256, 0, stream>>>(p, ei2, aggp, cnt2);
    }
    {   // out = aggp/cnt2 + h[:NTGT] @ Wr2 + b2
        dim3 grid((NTGT + BM - 1) / BM, 1);
        final_kernel<<<grid, 256, 0, stream>>>(h, Wr2, b2, aggp, cnt2, out);
    }
}

// Round 2
// 838.132 us; speedup vs baseline: 4.5942x; 4.5942x over previous
//
#include <hip/hip_runtime.h>

// GraphSAGE 2-layer. Round 2: replace fp32 atomic scatters with CSR gathers.
// Layer1: CSR(ei1) -> gather-mean x into aggn [100K,128]; h = relu([aggn|x]@[Wl1;Wr1]+b1)
// Layer2: p = h@Wl2 (project before aggregate: mean commutes with linear);
//         CSR(ei2) -> gather-mean p into aggp; out = aggp + h[:50K]@Wr2 + b2

#define NSRC 200000
#define NMID 100000
#define NTGT 50000
#define NE1  1600000
#define NE2  800000
#define DIN  128
#define DHID 256
#define DOUT 64

#define BM 64
#define BN 64
#define KT 16

// ---------------- CSR build ----------------

__global__ __launch_bounds__(256) void hist_kernel(
    const int* __restrict__ ei, int* __restrict__ cnt, int nE)
{
    int e = blockIdx.x * 256 + threadIdx.x;
    if (e < nE) atomicAdd(&cnt[ei[nE + e]], 1);
}

// chunk = 1024 elements per block (256 thr x 4)
__global__ __launch_bounds__(256) void scan_reduce_kernel(
    const int* __restrict__ cnt, int* __restrict__ bsum, int n)
{
    __shared__ int sdata[256];
    int base = blockIdx.x * 1024;
    int t = threadIdx.x;
    int s = 0;
    #pragma unroll
    for (int i = 0; i < 4; ++i) {
        int idx = base + t * 4 + i;
        s += (idx < n) ? cnt[idx] : 0;
    }
    sdata[t] = s; __syncthreads();
    for (int off = 128; off > 0; off >>= 1) {
        if (t < off) sdata[t] += sdata[t + off];
        __syncthreads();
    }
    if (t == 0) bsum[blockIdx.x] = sdata[0];
}

// single block, nb <= 256: in-place exclusive scan of block sums
__global__ __launch_bounds__(256) void scan_top_kernel(int* __restrict__ bsum, int nb)
{
    __shared__ int s[256];
    int t = threadIdx.x;
    s[t] = (t < nb) ? bsum[t] : 0;
    __syncthreads();
    for (int off = 1; off < 256; off <<= 1) {
        int v = (t >= off) ? s[t - off] : 0;
        __syncthreads();
        s[t] += v;
        __syncthreads();
    }
    if (t < nb) bsum[t] = (t == 0) ? 0 : s[t - 1];
}

__global__ __launch_bounds__(256) void scan_apply_kernel(
    const int* __restrict__ cnt, const int* __restrict__ bsum,
    int* __restrict__ rs, int n)
{
    __shared__ int s[256];
    int base = blockIdx.x * 1024;
    int t = threadIdx.x;
    int idx0 = base + t * 4;
    int v[4]; int sum = 0;
    #pragma unroll
    for (int i = 0; i < 4; ++i) {
        int id = idx0 + i;
        v[i] = (id < n) ? cnt[id] : 0;
        sum += v[i];
    }
    s[t] = sum; __syncthreads();
    for (int off = 1; off < 256; off <<= 1) {
        int u = (t >= off) ? s[t - off] : 0;
        __syncthreads();
        s[t] += u;
        __syncthreads();
    }
    int run = bsum[blockIdx.x] + ((t == 0) ? 0 : s[t - 1]);
    #pragma unroll
    for (int i = 0; i < 4; ++i) {
        int id = idx0 + i;
        if (id < n) rs[id] = run;
        run += v[i];
    }
}

// cur must be zeroed before this; after it, cur[t] == degree(t) again
__global__ __launch_bounds__(256) void csr_fill_kernel(
    const int* __restrict__ ei, const int* __restrict__ rs,
    int* __restrict__ cur, int* __restrict__ csr, int nE)
{
    int e = blockIdx.x * 256 + threadIdx.x;
    if (e >= nE) return;
    int src = ei[e];
    int tgt = ei[nE + e];
    int pos = atomicAdd(&cur[tgt], 1);
    csr[rs[tgt] + pos] = src;
}

// ---------------- gathers (one wave per target node) ----------------

// D=128: each lane owns float2 at offset lane*2; writes normalized mean.
__global__ __launch_bounds__(256) void gather1_kernel(
    const float* __restrict__ x, const int* __restrict__ rs,
    const int* __restrict__ cnt, const int* __restrict__ csr,
    float* __restrict__ aggn)
{
    int node = blockIdx.x * 4 + (threadIdx.x >> 6);
    if (node >= NMID) return;
    int lane = threadIdx.x & 63;
    int s = rs[node], d = cnt[node];
    float2 acc0 = {0.f, 0.f}, acc1 = {0.f, 0.f};
    int j = 0;
    for (; j + 1 < d; j += 2) {
        int s0 = csr[s + j], s1 = csr[s + j + 1];
        float2 v0 = *(const float2*)(x + (long long)s0 * DIN + lane * 2);
        float2 v1 = *(const float2*)(x + (long long)s1 * DIN + lane * 2);
        acc0.x += v0.x; acc0.y += v0.y;
        acc1.x += v1.x; acc1.y += v1.y;
    }
    if (j < d) {
        int s0 = csr[s + j];
        float2 v0 = *(const float2*)(x + (long long)s0 * DIN + lane * 2);
        acc0.x += v0.x; acc0.y += v0.y;
    }
    float inv = 1.0f / fmaxf((float)d, 1.0f);
    float2 r = {(acc0.x + acc1.x) * inv, (acc0.y + acc1.y) * inv};
    *(float2*)(aggn + (long long)node * DIN + lane * 2) = r;
}

// D=64: each lane owns one float.
__global__ __launch_bounds__(256) void gather2_kernel(
    const float* __restrict__ p, const int* __restrict__ rs,
    const int* __restrict__ cnt, const int* __restrict__ csr,
    float* __restrict__ aggp)
{
    int node = blockIdx.x * 4 + (threadIdx.x >> 6);
    if (node >= NTGT) return;
    int lane = threadIdx.x & 63;
    int s = rs[node], d = cnt[node];
    float acc0 = 0.f, acc1 = 0.f;
    int j = 0;
    for (; j + 1 < d; j += 2) {
        int s0 = csr[s + j], s1 = csr[s + j + 1];
        acc0 += p[(long long)s0 * DOUT + lane];
        acc1 += p[(long long)s1 * DOUT + lane];
    }
    if (j < d) acc0 += p[(long long)csr[s + j] * DOUT + lane];
    float inv = 1.0f / fmaxf((float)d, 1.0f);
    aggp[(long long)node * DOUT + lane] = (acc0 + acc1) * inv;
}

// ---------------- GEMMs (unchanged from round 1) ----------------

__global__ __launch_bounds__(256) void gemm1_kernel(
    const float* __restrict__ aggn, const float* __restrict__ x,
    const float* __restrict__ Wl, const float* __restrict__ Wr,
    const float* __restrict__ bias, float* __restrict__ h)
{
    __shared__ float As[KT][BM + 4];
    __shared__ float Bs[KT][BN + 4];
    int bm = blockIdx.x * BM;
    int bn = blockIdx.y * BN;
    int tid = threadIdx.x;
    int tx = tid & 15, ty = tid >> 4;
    int lr = tid >> 2;
    int lk = (tid & 3) * 4;
    int lbk = tid >> 4;
    int lbn = (tid & 15) * 4;
    float acc[4][4] = {};
    for (int k0 = 0; k0 < 2 * DIN; k0 += KT) {
        int grow = bm + lr;
        int gk = k0 + lk;
        float4 av = {0.f, 0.f, 0.f, 0.f};
        if (grow < NMID) {
            const float* Asrc = (gk < DIN) ? (aggn + (long long)grow * DIN + gk)
                                           : (x + (long long)grow * DIN + (gk - DIN));
            av = *(const float4*)Asrc;
        }
        As[lk + 0][lr] = av.x; As[lk + 1][lr] = av.y;
        As[lk + 2][lr] = av.z; As[lk + 3][lr] = av.w;
        int gbk = k0 + lbk;
        const float* Bsrc = (gbk < DIN) ? (Wl + (long long)gbk * DHID)
                                        : (Wr + (long long)(gbk - DIN) * DHID);
        *(float4*)&Bs[lbk][lbn] = *(const float4*)(Bsrc + bn + lbn);
        __syncthreads();
        #pragma unroll
        for (int kk = 0; kk < KT; ++kk) {
            float4 a = *(float4*)&As[kk][ty * 4];
            float4 b = *(float4*)&Bs[kk][tx * 4];
            float aa[4] = {a.x, a.y, a.z, a.w};
            float bb[4] = {b.x, b.y, b.z, b.w};
            #pragma unroll
            for (int i = 0; i < 4; ++i)
                #pragma unroll
                for (int j = 0; j < 4; ++j)
                    acc[i][j] += aa[i] * bb[j];
        }
        __syncthreads();
    }
    #pragma unroll
    for (int i = 0; i < 4; ++i) {
        int row = bm + ty * 4 + i;
        if (row >= NMID) continue;
        #pragma unroll
        for (int j = 0; j < 4; ++j) {
            int col = bn + tx * 4 + j;
            float v = acc[i][j] + bias[col];
            h[(long long)row * DHID + col] = fmaxf(v, 0.0f);
        }
    }
}

__global__ __launch_bounds__(256) void gemm2_kernel(
    const float* __restrict__ h, const float* __restrict__ W,
    float* __restrict__ p)
{
    __shared__ float As[KT][BM + 4];
    __shared__ float Bs[KT][BN + 4];
    int bm = blockIdx.x * BM;
    int tid = threadIdx.x;
    int tx = tid & 15, ty = tid >> 4;
    int lr = tid >> 2;
    int lk = (tid & 3) * 4;
    int lbk = tid >> 4;
    int lbn = (tid & 15) * 4;
    float acc[4][4] = {};
    for (int k0 = 0; k0 < DHID; k0 += KT) {
        int grow = bm + lr;
        int gk = k0 + lk;
        float4 av = {0.f, 0.f, 0.f, 0.f};
        if (grow < NMID) av = *(const float4*)(h + (long long)grow * DHID + gk);
        As[lk + 0][lr] = av.x; As[lk + 1][lr] = av.y;
        As[lk + 2][lr] = av.z; As[lk + 3][lr] = av.w;
        int gbk = k0 + lbk;
        *(float4*)&Bs[lbk][lbn] = *(const float4*)(W + (long long)gbk * DOUT + lbn);
        __syncthreads();
        #pragma unroll
        for (int kk = 0; kk < KT; ++kk) {
            float4 a = *(float4*)&As[kk][ty * 4];
            float4 b = *(float4*)&Bs[kk][tx * 4];
            float aa[4] = {a.x, a.y, a.z, a.w};
            float bb[4] = {b.x, b.y, b.z, b.w};
            #pragma unroll
            for (int i = 0; i < 4; ++i)
                #pragma unroll
                for (int j = 0; j < 4; ++j)
                    acc[i][j] += aa[i] * bb[j];
        }
        __syncthreads();
    }
    #pragma unroll
    for (int i = 0; i < 4; ++i) {
        int row = bm + ty * 4 + i;
        if (row >= NMID) continue;
        #pragma unroll
        for (int j = 0; j < 4; ++j) {
            int col = tx * 4 + j;
            p[(long long)row * DOUT + col] = acc[i][j];
        }
    }
}

__global__ __launch_bounds__(256) void final_kernel(
    const float* __restrict__ h, const float* __restrict__ W,
    const float* __restrict__ bias, const float* __restrict__ aggp,
    float* __restrict__ out)
{
    __shared__ float As[KT][BM + 4];
    __shared__ float Bs[KT][BN + 4];
    int bm = blockIdx.x * BM;
    int tid = threadIdx.x;
    int tx = tid & 15, ty = tid >> 4;
    int lr = tid >> 2;
    int lk = (tid & 3) * 4;
    int lbk = tid >> 4;
    int lbn = (tid & 15) * 4;
    float acc[4][4] = {};
    for (int k0 = 0; k0 < DHID; k0 += KT) {
        int grow = bm + lr;
        int gk = k0 + lk;
        float4 av = {0.f, 0.f, 0.f, 0.f};
        if (grow < NTGT) av = *(const float4*)(h + (long long)grow * DHID + gk);
        As[lk + 0][lr] = av.x; As[lk + 1][lr] = av.y;
        As[lk + 2][lr] = av.z; As[lk + 3][lr] = av.w;
        int gbk = k0 + lbk;
        *(float4*)&Bs[lbk][lbn] = *(const float4*)(W + (long long)gbk * DOUT + lbn);
        __syncthreads();
        #pragma unroll
        for (int kk = 0; kk < KT; ++kk) {
            float4 a = *(float4*)&As[kk][ty * 4];
            float4 b = *(float4*)&Bs[kk][tx * 4];
            float aa[4] = {a.x, a.y, a.z, a.w};
            float bb[4] = {b.x, b.y, b.z, b.w};
            #pragma unroll
            for (int i = 0; i < 4; ++i)
                #pragma unroll
                for (int j = 0; j < 4; ++j)
                    acc[i][j] += aa[i] * bb[j];
        }
        __syncthreads();
    }
    #pragma unroll
    for (int i = 0; i < 4; ++i) {
        int row = bm + ty * 4 + i;
        if (row >= NTGT) continue;
        #pragma unroll
        for (int j = 0; j < 4; ++j) {
            int col = tx * 4 + j;
            out[(long long)row * DOUT + col] =
                acc[i][j] + bias[col] + aggp[(long long)row * DOUT + col];
        }
    }
}

extern "C" void kernel_launch(void* const* d_in, const int* in_sizes, int n_in,
                              void* d_out, int out_size, void* d_ws, size_t ws_size,
                              hipStream_t stream) {
    const float* x   = (const float*)d_in[0];
    const int*   ei1 = (const int*)d_in[1];
    const int*   ei2 = (const int*)d_in[2];
    const float* Wl1 = (const float*)d_in[3];
    const float* Wr1 = (const float*)d_in[4];
    const float* b1  = (const float*)d_in[5];
    const float* Wl2 = (const float*)d_in[6];
    const float* Wr2 = (const float*)d_in[7];
    const float* b2  = (const float*)d_in[8];
    float* out = (float*)d_out;

    // ws layout: ints first (16B-aligned total), then floats
    int* cnt1  = (int*)d_ws;
    int* rs1   = cnt1 + NMID;
    int* csr1  = rs1 + NMID;
    int* bsum1 = csr1 + NE1;
    int* cnt2  = bsum1 + 256;
    int* rs2   = cnt2 + NTGT;
    int* csr2  = rs2 + NTGT;
    int* bsum2 = csr2 + NE2;
    float* aggn = (float*)(bsum2 + 256);          // [NMID, DIN]
    float* h    = aggn + (size_t)NMID * DIN;      // [NMID, DHID]
    float* p    = h + (size_t)NMID * DHID;        // [NMID, DOUT]
    float* aggp = p + (size_t)NMID * DOUT;        // [NTGT, DOUT]

    const int nb1 = (NMID + 1023) / 1024;  // 98
    const int nb2 = (NTGT + 1023) / 1024;  // 49

    // ---- CSR build, layer 1 ----
    hipMemsetAsync(cnt1, 0, NMID * 4, stream);
    hist_kernel<<<(NE1 + 255) / 256, 256, 0, stream>>>(ei1, cnt1, NE1);
    scan_reduce_kernel<<<nb1, 256, 0, stream>>>(cnt1, bsum1, NMID);
    scan_top_kernel<<<1, 256, 0, stream>>>(bsum1, nb1);
    scan_apply_kernel<<<nb1, 256, 0, stream>>>(cnt1, bsum1, rs1, NMID);
    hipMemsetAsync(cnt1, 0, NMID * 4, stream);
    csr_fill_kernel<<<(NE1 + 255) / 256, 256, 0, stream>>>(ei1, rs1, cnt1, csr1, NE1);

    // ---- CSR build, layer 2 ----
    hipMemsetAsync(cnt2, 0, NTGT * 4, stream);
    hist_kernel<<<(NE2 + 255) / 256, 256, 0, stream>>>(ei2, cnt2, NE2);
    scan_reduce_kernel<<<nb2, 256, 0, stream>>>(cnt2, bsum2, NTGT);
    scan_top_kernel<<<1, 256, 0, stream>>>(bsum2, nb2);
    scan_apply_kernel<<<nb2, 256, 0, stream>>>(cnt2, bsum2, rs2, NTGT);
    hipMemsetAsync(cnt2, 0, NTGT * 4, stream);
    csr_fill_kernel<<<(NE2 + 255) / 256, 256, 0, stream>>>(ei2, rs2, cnt2, csr2, NE2);

    // ---- layer 1 ----
    gather1_kernel<<<(NMID + 3) / 4, 256, 0, stream>>>(x, rs1, cnt1, csr1, aggn);
    {
        dim3 grid((NMID + BM - 1) / BM, DHID / BN);
        gemm1_kernel<<<grid, 256, 0, stream>>>(aggn, x, Wl1, Wr1, b1, h);
    }

    // ---- layer 2 ----
    {
        dim3 grid((NMID + BM - 1) / BM, 1);
        gemm2_kernel<<<grid, 256, 0, stream>>>(h, Wl2, p);
    }
    gather2_kernel<<<(NTGT + 3) / 4, 256, 0, stream>>>(p, rs2, cnt2, csr2, aggp);
    {
        dim3 grid((NTGT + BM - 1) / BM, 1);
        final_kernel<<<grid, 256, 0, stream>>>(h, Wr2, b2, aggp, out);
    }
}

// Round 3
// 657.355 us; speedup vs baseline: 5.8576x; 1.2750x over previous
//
#include <hip/hip_runtime.h>

// GraphSAGE 2-layer. Round 3: bf16 MFMA GEMMs + bf16 gather traffic.
// Layer1: CSR(ei1) -> gather-mean xb(bf16) into aggnb; h = relu([aggnb|xb]@[Wl1;Wr1]+b1) via MFMA, h bf16
// Layer2: p = h@Wl2 (MFMA, fp32 out); CSR(ei2) gather-mean p -> aggp;
//         out = aggp + h[:50K]@Wr2 + b2 (MFMA epilogue fused)

#define NSRC 200000
#define NMID 100000
#define NTGT 50000
#define NE1  1600000
#define NE2  800000
#define DIN  128
#define DHID 256
#define DOUT 64

typedef __attribute__((ext_vector_type(8))) short bf16x8;
typedef __attribute__((ext_vector_type(4))) float f32x4;

__device__ __forceinline__ unsigned short f2bf(float f) {
    unsigned int u = __builtin_bit_cast(unsigned int, f);
    u += 0x7FFFu + ((u >> 16) & 1u);
    return (unsigned short)(u >> 16);
}
__device__ __forceinline__ float bf2f(unsigned short s) {
    unsigned int u = ((unsigned int)s) << 16;
    return __builtin_bit_cast(float, u);
}

// ---------------- converts ----------------

// xb[m][k] = bf16(x[m][k]) for all NSRC rows; 8 elems/thread
__global__ __launch_bounds__(256) void convert_x_kernel(
    const float* __restrict__ x, unsigned short* __restrict__ xb)
{
    int gid = blockIdx.x * 256 + threadIdx.x;          // NSRC*16 chunks
    if (gid >= NSRC * 16) return;
    const float4 v0 = *(const float4*)(x + (long long)gid * 8);
    const float4 v1 = *(const float4*)(x + (long long)gid * 8 + 4);
    unsigned short o[8] = {f2bf(v0.x), f2bf(v0.y), f2bf(v0.z), f2bf(v0.w),
                           f2bf(v1.x), f2bf(v1.y), f2bf(v1.z), f2bf(v1.w)};
    *(uint4*)(xb + (long long)gid * 8) = *(const uint4*)o;
}

// WT1[n][k] = bf16( k<128 ? Wl1[k][n] : Wr1[k-128][n] ), n<256, k<256
__global__ __launch_bounds__(256) void convert_w1_kernel(
    const float* __restrict__ Wl, const float* __restrict__ Wr,
    unsigned short* __restrict__ WT)
{
    int gid = blockIdx.x * 256 + threadIdx.x;   // 65536
    int n = gid >> 8, k = gid & 255;
    float v = (k < DIN) ? Wl[(long long)k * DHID + n] : Wr[(long long)(k - DIN) * DHID + n];
    WT[gid] = f2bf(v);
}

// WT2[n2][k]: n2<64 -> Wl2[k][n2] ; n2 in [64,128) -> Wr2[k][n2-64]; k<256
__global__ __launch_bounds__(256) void convert_w2_kernel(
    const float* __restrict__ Wl, const float* __restrict__ Wr,
    unsigned short* __restrict__ WT)
{
    int gid = blockIdx.x * 256 + threadIdx.x;   // 32768
    int n2 = gid >> 8, k = gid & 255;
    float v = (n2 < DOUT) ? Wl[(long long)k * DOUT + n2] : Wr[(long long)k * DOUT + (n2 - DOUT)];
    WT[gid] = f2bf(v);
}

// ---------------- CSR build ----------------

__global__ __launch_bounds__(256) void hist_kernel(
    const int* __restrict__ ei, int* __restrict__ cnt, int nE)
{
    int e = blockIdx.x * 256 + threadIdx.x;
    if (e < nE) atomicAdd(&cnt[ei[nE + e]], 1);
}

__global__ __launch_bounds__(256) void scan_reduce_kernel(
    const int* __restrict__ cnt, int* __restrict__ bsum, int n)
{
    __shared__ int sdata[256];
    int base = blockIdx.x * 1024;
    int t = threadIdx.x;
    int s = 0;
    #pragma unroll
    for (int i = 0; i < 4; ++i) {
        int idx = base + t * 4 + i;
        s += (idx < n) ? cnt[idx] : 0;
    }
    sdata[t] = s; __syncthreads();
    for (int off = 128; off > 0; off >>= 1) {
        if (t < off) sdata[t] += sdata[t + off];
        __syncthreads();
    }
    if (t == 0) bsum[blockIdx.x] = sdata[0];
}

__global__ __launch_bounds__(256) void scan_top_kernel(int* __restrict__ bsum, int nb)
{
    __shared__ int s[256];
    int t = threadIdx.x;
    s[t] = (t < nb) ? bsum[t] : 0;
    __syncthreads();
    for (int off = 1; off < 256; off <<= 1) {
        int v = (t >= off) ? s[t - off] : 0;
        __syncthreads();
        s[t] += v;
        __syncthreads();
    }
    if (t < nb) bsum[t] = (t == 0) ? 0 : s[t - 1];
}

__global__ __launch_bounds__(256) void scan_apply_kernel(
    const int* __restrict__ cnt, const int* __restrict__ bsum,
    int* __restrict__ rs, int n)
{
    __shared__ int s[256];
    int base = blockIdx.x * 1024;
    int t = threadIdx.x;
    int idx0 = base + t * 4;
    int v[4]; int sum = 0;
    #pragma unroll
    for (int i = 0; i < 4; ++i) {
        int id = idx0 + i;
        v[i] = (id < n) ? cnt[id] : 0;
        sum += v[i];
    }
    s[t] = sum; __syncthreads();
    for (int off = 1; off < 256; off <<= 1) {
        int u = (t >= off) ? s[t - off] : 0;
        __syncthreads();
        s[t] += u;
        __syncthreads();
    }
    int run = bsum[blockIdx.x] + ((t == 0) ? 0 : s[t - 1]);
    #pragma unroll
    for (int i = 0; i < 4; ++i) {
        int id = idx0 + i;
        if (id < n) rs[id] = run;
        run += v[i];
    }
}

__global__ __launch_bounds__(256) void csr_fill_kernel(
    const int* __restrict__ ei, const int* __restrict__ rs,
    int* __restrict__ cur, int* __restrict__ csr, int nE)
{
    int e = blockIdx.x * 256 + threadIdx.x;
    if (e >= nE) return;
    int src = ei[e];
    int tgt = ei[nE + e];
    int pos = atomicAdd(&cur[tgt], 1);
    csr[rs[tgt] + pos] = src;
}

// ---------------- gathers ----------------

// one wave per node; lane owns 2 bf16 elems (one u32 load per edge)
__global__ __launch_bounds__(256) void gather1_kernel(
    const unsigned short* __restrict__ xb, const int* __restrict__ rs,
    const int* __restrict__ cnt, const int* __restrict__ csr,
    unsigned short* __restrict__ aggnb)
{
    int node = blockIdx.x * 4 + (threadIdx.x >> 6);
    if (node >= NMID) return;
    int lane = threadIdx.x & 63;
    int s = rs[node], d = cnt[node];
    float a0 = 0.f, a1 = 0.f, b0 = 0.f, b1 = 0.f;
    int j = 0;
    for (; j + 1 < d; j += 2) {
        int s0 = csr[s + j], s1 = csr[s + j + 1];
        unsigned int u0 = *(const unsigned int*)(xb + (long long)s0 * DIN + lane * 2);
        unsigned int u1 = *(const unsigned int*)(xb + (long long)s1 * DIN + lane * 2);
        a0 += bf2f((unsigned short)u0); a1 += bf2f((unsigned short)(u0 >> 16));
        b0 += bf2f((unsigned short)u1); b1 += bf2f((unsigned short)(u1 >> 16));
    }
    if (j < d) {
        unsigned int u0 = *(const unsigned int*)(xb + (long long)csr[s + j] * DIN + lane * 2);
        a0 += bf2f((unsigned short)u0); a1 += bf2f((unsigned short)(u0 >> 16));
    }
    float inv = 1.0f / fmaxf((float)d, 1.0f);
    unsigned int packed = (unsigned int)f2bf((a0 + b0) * inv)
                        | ((unsigned int)f2bf((a1 + b1) * inv) << 16);
    *(unsigned int*)(aggnb + (long long)node * DIN + lane * 2) = packed;
}

// one wave per node; lane owns 1 fp32 elem of p (D=64)
__global__ __launch_bounds__(256) void gather2_kernel(
    const float* __restrict__ p, const int* __restrict__ rs,
    const int* __restrict__ cnt, const int* __restrict__ csr,
    float* __restrict__ aggp)
{
    int node = blockIdx.x * 4 + (threadIdx.x >> 6);
    if (node >= NTGT) return;
    int lane = threadIdx.x & 63;
    int s = rs[node], d = cnt[node];
    float acc0 = 0.f, acc1 = 0.f;
    int j = 0;
    for (; j + 1 < d; j += 2) {
        int s0 = csr[s + j], s1 = csr[s + j + 1];
        acc0 += p[(long long)s0 * DOUT + lane];
        acc1 += p[(long long)s1 * DOUT + lane];
    }
    if (j < d) acc0 += p[(long long)csr[s + j] * DOUT + lane];
    float inv = 1.0f / fmaxf((float)d, 1.0f);
    aggp[(long long)node * DOUT + lane] = (acc0 + acc1) * inv;
}

// ---------------- MFMA GEMMs ----------------
// LDS row stride 40 bf16 (80 B): 16B-aligned, 2-way bank alias only.
#define LDSP 40

// h = relu([aggnb | xb] @ W1 + b1); A k<128 from aggnb, else xb. M=NMID,K=256,N=256
// block 128x128, 4 waves in 2x2; wave tile 64x64 = 4x4 frags of 16x16
__global__ __launch_bounds__(256) void gemm1_mfma(
    const unsigned short* __restrict__ aggnb, const unsigned short* __restrict__ xb,
    const unsigned short* __restrict__ WT, const float* __restrict__ bias,
    unsigned short* __restrict__ h)
{
    __shared__ unsigned short Asm[128 * LDSP];
    __shared__ unsigned short Bsm[128 * LDSP];
    const int tid = threadIdx.x;
    const int bm = blockIdx.x * 128;
    const int bn = blockIdx.y * 128;
    const int wave = tid >> 6, lane = tid & 63;
    const int wr = wave >> 1, wc = wave & 1;
    const int lrow = lane & 15, quad = lane >> 4;

    f32x4 acc[4][4];
    #pragma unroll
    for (int i = 0; i < 4; ++i)
        #pragma unroll
        for (int j = 0; j < 4; ++j)
            acc[i][j] = (f32x4){0.f, 0.f, 0.f, 0.f};

    for (int k0 = 0; k0 < 256; k0 += 32) {
        // stage A: 128 rows x 32 k = 512 16B-chunks
        #pragma unroll
        for (int c = tid; c < 512; c += 256) {
            int row = c >> 2, seg = c & 3;
            int grow = bm + row; if (grow >= NMID) grow = NMID - 1;
            int gk = k0 + seg * 8;
            const unsigned short* src = (gk < DIN)
                ? (aggnb + (long long)grow * DIN + gk)
                : (xb + (long long)grow * DIN + (gk - DIN));
            *(uint4*)(Asm + row * LDSP + seg * 8) = *(const uint4*)src;
        }
        // stage B (WT rows = n, contiguous k)
        #pragma unroll
        for (int c = tid; c < 512; c += 256) {
            int row = c >> 2, seg = c & 3;
            *(uint4*)(Bsm + row * LDSP + seg * 8) =
                *(const uint4*)(WT + (long long)(bn + row) * 256 + k0 + seg * 8);
        }
        __syncthreads();
        bf16x8 af[4], bf[4];
        #pragma unroll
        for (int mi = 0; mi < 4; ++mi)
            af[mi] = *(const bf16x8*)(Asm + (wr * 64 + mi * 16 + lrow) * LDSP + quad * 8);
        #pragma unroll
        for (int ni = 0; ni < 4; ++ni)
            bf[ni] = *(const bf16x8*)(Bsm + (wc * 64 + ni * 16 + lrow) * LDSP + quad * 8);
        #pragma unroll
        for (int mi = 0; mi < 4; ++mi)
            #pragma unroll
            for (int ni = 0; ni < 4; ++ni)
                acc[mi][ni] = __builtin_amdgcn_mfma_f32_16x16x32_bf16(
                    af[mi], bf[ni], acc[mi][ni], 0, 0, 0);
        __syncthreads();
    }
    // epilogue: C[row][col], col=lane&15, row=quad*4+r
    #pragma unroll
    for (int mi = 0; mi < 4; ++mi) {
        #pragma unroll
        for (int ni = 0; ni < 4; ++ni) {
            int col = bn + wc * 64 + ni * 16 + lrow;
            float bv = bias[col];
            #pragma unroll
            for (int r = 0; r < 4; ++r) {
                int row = bm + wr * 64 + mi * 16 + quad * 4 + r;
                if (row < NMID) {
                    float v = acc[mi][ni][r] + bv;
                    h[(long long)row * DHID + col] = f2bf(fmaxf(v, 0.0f));
                }
            }
        }
    }
}

// C = h[mrange] @ WT[nofs..nofs+64) (+ b2 + aggp if FIN). M rows, N=64, K=256.
// block 128 rows; 4 waves stacked: wave w rows [w*32, w*32+32), frags 2x4
template <bool FIN>
__global__ __launch_bounds__(256) void gemm_n64_mfma(
    const unsigned short* __restrict__ h, const unsigned short* __restrict__ WT,
    int nofs, int M,
    const float* __restrict__ bias, const float* __restrict__ aggp,
    float* __restrict__ outp)
{
    __shared__ unsigned short Asm[128 * LDSP];
    __shared__ unsigned short Bsm[64 * LDSP];
    const int tid = threadIdx.x;
    const int bm = blockIdx.x * 128;
    const int wave = tid >> 6, lane = tid & 63;
    const int lrow = lane & 15, quad = lane >> 4;

    f32x4 acc[2][4];
    #pragma unroll
    for (int i = 0; i < 2; ++i)
        #pragma unroll
        for (int j = 0; j < 4; ++j)
            acc[i][j] = (f32x4){0.f, 0.f, 0.f, 0.f};

    for (int k0 = 0; k0 < 256; k0 += 32) {
        #pragma unroll
        for (int c = tid; c < 512; c += 256) {
            int row = c >> 2, seg = c & 3;
            int grow = bm + row; if (grow >= M) grow = M - 1;
            *(uint4*)(Asm + row * LDSP + seg * 8) =
                *(const uint4*)(h + (long long)grow * DHID + k0 + seg * 8);
        }
        {
            int row = tid >> 2, seg = tid & 3;   // 64 rows x 4 segs = 256
            *(uint4*)(Bsm + row * LDSP + seg * 8) =
                *(const uint4*)(WT + (long long)(nofs + row) * 256 + k0 + seg * 8);
        }
        __syncthreads();
        bf16x8 af[2], bf[4];
        #pragma unroll
        for (int mi = 0; mi < 2; ++mi)
            af[mi] = *(const bf16x8*)(Asm + (wave * 32 + mi * 16 + lrow) * LDSP + quad * 8);
        #pragma unroll
        for (int ni = 0; ni < 4; ++ni)
            bf[ni] = *(const bf16x8*)(Bsm + (ni * 16 + lrow) * LDSP + quad * 8);
        #pragma unroll
        for (int mi = 0; mi < 2; ++mi)
            #pragma unroll
            for (int ni = 0; ni < 4; ++ni)
                acc[mi][ni] = __builtin_amdgcn_mfma_f32_16x16x32_bf16(
                    af[mi], bf[ni], acc[mi][ni], 0, 0, 0);
        __syncthreads();
    }
    #pragma unroll
    for (int mi = 0; mi < 2; ++mi) {
        #pragma unroll
        for (int ni = 0; ni < 4; ++ni) {
            int col = ni * 16 + lrow;
            float bv = FIN ? bias[col] : 0.f;
            #pragma unroll
            for (int r = 0; r < 4; ++r) {
                int row = bm + wave * 32 + mi * 16 + quad * 4 + r;
                if (row < M) {
                    float v = acc[mi][ni][r] + bv;
                    if (FIN) v += aggp[(long long)row * DOUT + col];
                    outp[(long long)row * DOUT + col] = v;
                }
            }
        }
    }
}

extern "C" void kernel_launch(void* const* d_in, const int* in_sizes, int n_in,
                              void* d_out, int out_size, void* d_ws, size_t ws_size,
                              hipStream_t stream) {
    const float* x   = (const float*)d_in[0];
    const int*   ei1 = (const int*)d_in[1];
    const int*   ei2 = (const int*)d_in[2];
    const float* Wl1 = (const float*)d_in[3];
    const float* Wr1 = (const float*)d_in[4];
    const float* b1  = (const float*)d_in[5];
    const float* Wl2 = (const float*)d_in[6];
    const float* Wr2 = (const float*)d_in[7];
    const float* b2  = (const float*)d_in[8];
    float* out = (float*)d_out;

    // ints
    int* cnt1  = (int*)d_ws;
    int* rs1   = cnt1 + NMID;
    int* csr1  = rs1 + NMID;
    int* bsum1 = csr1 + NE1;
    int* cnt2  = bsum1 + 256;
    int* rs2   = cnt2 + NTGT;
    int* csr2  = rs2 + NTGT;
    int* bsum2 = csr2 + NE2;
    // bf16
    unsigned short* xb    = (unsigned short*)(bsum2 + 256);
    unsigned short* aggnb = xb + (size_t)NSRC * DIN;
    unsigned short* h     = aggnb + (size_t)NMID * DIN;
    unsigned short* WT1   = h + (size_t)NMID * DHID;
    unsigned short* WT2   = WT1 + 256 * 256;
    // fp32
    float* p    = (float*)(WT2 + 128 * 256);
    float* aggp = p + (size_t)NMID * DOUT;

    const int nb1 = (NMID + 1023) / 1024;
    const int nb2 = (NTGT + 1023) / 1024;

    // converts (independent of CSR)
    convert_x_kernel<<<(NSRC * 16 + 255) / 256, 256, 0, stream>>>(x, xb);
    convert_w1_kernel<<<256, 256, 0, stream>>>(Wl1, Wr1, WT1);
    convert_w2_kernel<<<128, 256, 0, stream>>>(Wl2, Wr2, WT2);

    // CSR layer 1
    hipMemsetAsync(cnt1, 0, NMID * 4, stream);
    hist_kernel<<<(NE1 + 255) / 256, 256, 0, stream>>>(ei1, cnt1, NE1);
    scan_reduce_kernel<<<nb1, 256, 0, stream>>>(cnt1, bsum1, NMID);
    scan_top_kernel<<<1, 256, 0, stream>>>(bsum1, nb1);
    scan_apply_kernel<<<nb1, 256, 0, stream>>>(cnt1, bsum1, rs1, NMID);
    hipMemsetAsync(cnt1, 0, NMID * 4, stream);
    csr_fill_kernel<<<(NE1 + 255) / 256, 256, 0, stream>>>(ei1, rs1, cnt1, csr1, NE1);

    // CSR layer 2
    hipMemsetAsync(cnt2, 0, NTGT * 4, stream);
    hist_kernel<<<(NE2 + 255) / 256, 256, 0, stream>>>(ei2, cnt2, NE2);
    scan_reduce_kernel<<<nb2, 256, 0, stream>>>(cnt2, bsum2, NTGT);
    scan_top_kernel<<<1, 256, 0, stream>>>(bsum2, nb2);
    scan_apply_kernel<<<nb2, 256, 0, stream>>>(cnt2, bsum2, rs2, NTGT);
    hipMemsetAsync(cnt2, 0, NTGT * 4, stream);
    csr_fill_kernel<<<(NE2 + 255) / 256, 256, 0, stream>>>(ei2, rs2, cnt2, csr2, NE2);

    // layer 1
    gather1_kernel<<<(NMID + 3) / 4, 256, 0, stream>>>(xb, rs1, cnt1, csr1, aggnb);
    {
        dim3 grid((NMID + 127) / 128, 2);
        gemm1_mfma<<<grid, 256, 0, stream>>>(aggnb, xb, WT1, b1, h);
    }
    // layer 2
    gemm_n64_mfma<false><<<(NMID + 127) / 128, 256, 0, stream>>>(
        h, WT2, 0, NMID, nullptr, nullptr, p);
    gather2_kernel<<<(NTGT + 3) / 4, 256, 0, stream>>>(p, rs2, cnt2, csr2, aggp);
    gemm_n64_mfma<true><<<(NTGT + 127) / 128, 256, 0, stream>>>(
        h, WT2, 64, NTGT, b2, aggp, out);
}

// Round 4
// 577.711 us; speedup vs baseline: 6.6652x; 1.1379x over previous
//
#include <hip/hip_runtime.h>

// GraphSAGE 2-layer. Round 4: readlane-broadcast CSR gathers, fused CSR build,
// atomicSub fill (no cnt re-zero), fused converts. MFMA GEMMs unchanged.

#define NSRC 200000
#define NMID 100000
#define NTGT 50000
#define NE1  1600000
#define NE2  800000
#define DIN  128
#define DHID 256
#define DOUT 64

#define NB1 98   // (NMID+1023)/1024
#define NB2 49   // (NTGT+1023)/1024
#define XCH (NSRC * 16)

typedef __attribute__((ext_vector_type(8))) short bf16x8;
typedef __attribute__((ext_vector_type(4))) float f32x4;

__device__ __forceinline__ unsigned short f2bf(float f) {
    unsigned int u = __builtin_bit_cast(unsigned int, f);
    u += 0x7FFFu + ((u >> 16) & 1u);
    return (unsigned short)(u >> 16);
}
__device__ __forceinline__ float bf_lo(unsigned int u) {
    return __builtin_bit_cast(float, u << 16);
}
__device__ __forceinline__ float bf_hi(unsigned int u) {
    return __builtin_bit_cast(float, u & 0xFFFF0000u);
}

// ---------------- fused converts ----------------
__global__ __launch_bounds__(256) void convert_all_kernel(
    const float* __restrict__ x,
    const float* __restrict__ Wl1, const float* __restrict__ Wr1,
    const float* __restrict__ Wl2, const float* __restrict__ Wr2,
    unsigned short* __restrict__ xb, unsigned short* __restrict__ WT1,
    unsigned short* __restrict__ WT2)
{
    int gid = blockIdx.x * 256 + threadIdx.x;
    if (gid < XCH) {
        const float4 v0 = *(const float4*)(x + (long long)gid * 8);
        const float4 v1 = *(const float4*)(x + (long long)gid * 8 + 4);
        unsigned short o[8] = {f2bf(v0.x), f2bf(v0.y), f2bf(v0.z), f2bf(v0.w),
                               f2bf(v1.x), f2bf(v1.y), f2bf(v1.z), f2bf(v1.w)};
        *(uint4*)(xb + (long long)gid * 8) = *(const uint4*)o;
        return;
    }
    int g = gid - XCH;
    if (g < 65536) {  // WT1[n][k]
        int n = g >> 8, k = g & 255;
        float v = (k < DIN) ? Wl1[(long long)k * DHID + n]
                            : Wr1[(long long)(k - DIN) * DHID + n];
        WT1[g] = f2bf(v);
        return;
    }
    g -= 65536;
    if (g < 32768) {  // WT2[n2][k]
        int n2 = g >> 8, k = g & 255;
        float v = (n2 < DOUT) ? Wl2[(long long)k * DOUT + n2]
                              : Wr2[(long long)k * DOUT + (n2 - DOUT)];
        WT2[g] = f2bf(v);
    }
}

// ---------------- CSR build (fused both layers) ----------------

__global__ __launch_bounds__(256) void hist_both_kernel(
    const int* __restrict__ ei1, const int* __restrict__ ei2,
    int* __restrict__ cnt1, int* __restrict__ cnt2)
{
    int e = blockIdx.x * 256 + threadIdx.x;
    if (e < NE1) { atomicAdd(&cnt1[ei1[NE1 + e]], 1); return; }
    e -= NE1;
    if (e < NE2) atomicAdd(&cnt2[ei2[NE2 + e]], 1);
}

__global__ __launch_bounds__(256) void scan_reduce_both_kernel(
    const int* __restrict__ cnt1, const int* __restrict__ cnt2,
    int* __restrict__ bsum1, int* __restrict__ bsum2)
{
    const int* cnt; int* bsum; int n, bi;
    if (blockIdx.x < NB1) { cnt = cnt1; bsum = bsum1; n = NMID; bi = blockIdx.x; }
    else { cnt = cnt2; bsum = bsum2; n = NTGT; bi = blockIdx.x - NB1; }
    __shared__ int sdata[256];
    int base = bi * 1024;
    int t = threadIdx.x;
    int s = 0;
    #pragma unroll
    for (int i = 0; i < 4; ++i) {
        int idx = base + t * 4 + i;
        s += (idx < n) ? cnt[idx] : 0;
    }
    sdata[t] = s; __syncthreads();
    for (int off = 128; off > 0; off >>= 1) {
        if (t < off) sdata[t] += sdata[t + off];
        __syncthreads();
    }
    if (t == 0) bsum[bi] = sdata[0];
}

__global__ __launch_bounds__(256) void scan_top_both_kernel(
    int* __restrict__ bsum1, int* __restrict__ bsum2,
    int* __restrict__ rs1, int* __restrict__ rs2)
{
    __shared__ int sm[256];
    int t = threadIdx.x;
    sm[t] = (t < NB1) ? bsum1[t] : 0;
    __syncthreads();
    for (int off = 1; off < 256; off <<= 1) {
        int v = (t >= off) ? sm[t - off] : 0;
        __syncthreads();
        sm[t] += v;
        __syncthreads();
    }
    if (t < NB1) bsum1[t] = (t == 0) ? 0 : sm[t - 1];
    __syncthreads();
    sm[t] = (t < NB2) ? bsum2[t] : 0;
    __syncthreads();
    for (int off = 1; off < 256; off <<= 1) {
        int v = (t >= off) ? sm[t - off] : 0;
        __syncthreads();
        sm[t] += v;
        __syncthreads();
    }
    if (t < NB2) bsum2[t] = (t == 0) ? 0 : sm[t - 1];
    if (t == 0) { rs1[NMID] = NE1; rs2[NTGT] = NE2; }
}

__global__ __launch_bounds__(256) void scan_apply_both_kernel(
    const int* __restrict__ cnt1, const int* __restrict__ cnt2,
    const int* __restrict__ bsum1, const int* __restrict__ bsum2,
    int* __restrict__ rs1, int* __restrict__ rs2)
{
    const int* cnt; const int* bsum; int* rs; int n, bi;
    if (blockIdx.x < NB1) { cnt = cnt1; bsum = bsum1; rs = rs1; n = NMID; bi = blockIdx.x; }
    else { cnt = cnt2; bsum = bsum2; rs = rs2; n = NTGT; bi = blockIdx.x - NB1; }
    __shared__ int s[256];
    int base = bi * 1024;
    int t = threadIdx.x;
    int idx0 = base + t * 4;
    int v[4]; int sum = 0;
    #pragma unroll
    for (int i = 0; i < 4; ++i) {
        int id = idx0 + i;
        v[i] = (id < n) ? cnt[id] : 0;
        sum += v[i];
    }
    s[t] = sum; __syncthreads();
    for (int off = 1; off < 256; off <<= 1) {
        int u = (t >= off) ? s[t - off] : 0;
        __syncthreads();
        s[t] += u;
        __syncthreads();
    }
    int run = bsum[bi] + ((t == 0) ? 0 : s[t - 1]);
    #pragma unroll
    for (int i = 0; i < 4; ++i) {
        int id = idx0 + i;
        if (id < n) rs[id] = run;
        run += v[i];
    }
}

// atomicSub from degree: after this, cnt==0 everywhere (order within a node reversed — OK for sums)
__global__ __launch_bounds__(256) void fill_both_kernel(
    const int* __restrict__ ei1, const int* __restrict__ ei2,
    const int* __restrict__ rs1, const int* __restrict__ rs2,
    int* __restrict__ cnt1, int* __restrict__ cnt2,
    int* __restrict__ csr1, int* __restrict__ csr2)
{
    int e = blockIdx.x * 256 + threadIdx.x;
    if (e < NE1) {
        int src = ei1[e], tgt = ei1[NE1 + e];
        int pos = atomicSub(&cnt1[tgt], 1) - 1;
        csr1[rs1[tgt] + pos] = src;
        return;
    }
    e -= NE1;
    if (e < NE2) {
        int src = ei2[e], tgt = ei2[NE2 + e];
        int pos = atomicSub(&cnt2[tgt], 1) - 1;
        csr2[rs2[tgt] + pos] = src;
    }
}

// ---------------- gathers ----------------
// one wave per node; csr indices register-cached (64 at a time), broadcast via readlane,
// scalar-base loads, 4 independent accumulator chains.

__global__ __launch_bounds__(256) void gather1_kernel(
    const unsigned short* __restrict__ xb, const int* __restrict__ rs,
    const int* __restrict__ csr, unsigned short* __restrict__ aggnb)
{
    int node = blockIdx.x * 4 + (threadIdx.x >> 6);
    if (node >= NMID) return;
    int lane = threadIdx.x & 63;
    int s = rs[node];
    int d = rs[node + 1] - s;
    const char* xbase = (const char*)xb;
    unsigned int voff = (unsigned int)lane * 4u;
    float a0 = 0.f, a1 = 0.f, b0 = 0.f, b1 = 0.f;
    float c0 = 0.f, c1 = 0.f, e0 = 0.f, e1 = 0.f;
    for (int base = 0; base < d; base += 64) {
        int nb = d - base; if (nb > 64) nb = 64;
        int li = base + lane; if (li > d - 1) li = d - 1;
        int my = csr[s + li];
        int j = 0;
        for (; j + 3 < nb; j += 4) {
            int s0 = __builtin_amdgcn_readlane(my, j);
            int s1 = __builtin_amdgcn_readlane(my, j + 1);
            int s2 = __builtin_amdgcn_readlane(my, j + 2);
            int s3 = __builtin_amdgcn_readlane(my, j + 3);
            unsigned int u0 = *(const unsigned int*)(xbase + (((size_t)(unsigned)s0) << 8) + voff);
            unsigned int u1 = *(const unsigned int*)(xbase + (((size_t)(unsigned)s1) << 8) + voff);
            unsigned int u2 = *(const unsigned int*)(xbase + (((size_t)(unsigned)s2) << 8) + voff);
            unsigned int u3 = *(const unsigned int*)(xbase + (((size_t)(unsigned)s3) << 8) + voff);
            a0 += bf_lo(u0); a1 += bf_hi(u0);
            b0 += bf_lo(u1); b1 += bf_hi(u1);
            c0 += bf_lo(u2); c1 += bf_hi(u2);
            e0 += bf_lo(u3); e1 += bf_hi(u3);
        }
        for (; j < nb; ++j) {
            int s0 = __builtin_amdgcn_readlane(my, j);
            unsigned int u0 = *(const unsigned int*)(xbase + (((size_t)(unsigned)s0) << 8) + voff);
            a0 += bf_lo(u0); a1 += bf_hi(u0);
        }
    }
    float inv = (d > 0) ? 1.0f / (float)d : 0.f;
    float r0 = (a0 + b0 + c0 + e0) * inv;
    float r1 = (a1 + b1 + c1 + e1) * inv;
    unsigned int packed = (unsigned int)f2bf(r0) | ((unsigned int)f2bf(r1) << 16);
    *(unsigned int*)(aggnb + (long long)node * DIN + lane * 2) = packed;
}

// p rows are DOUT=64 fp32 = 256 B; lane owns one float (voff=lane*4), base = src<<8.
__global__ __launch_bounds__(256) void gather2_kernel(
    const float* __restrict__ p, const int* __restrict__ rs,
    const int* __restrict__ csr, float* __restrict__ aggp)
{
    int node = blockIdx.x * 4 + (threadIdx.x >> 6);
    if (node >= NTGT) return;
    int lane = threadIdx.x & 63;
    int s = rs[node];
    int d = rs[node + 1] - s;
    const char* pbase = (const char*)p;
    unsigned int voff = (unsigned int)lane * 4u;
    float a = 0.f, b = 0.f, c = 0.f, e = 0.f;
    for (int base = 0; base < d; base += 64) {
        int nb = d - base; if (nb > 64) nb = 64;
        int li = base + lane; if (li > d - 1) li = d - 1;
        int my = csr[s + li];
        int j = 0;
        for (; j + 3 < nb; j += 4) {
            int s0 = __builtin_amdgcn_readlane(my, j);
            int s1 = __builtin_amdgcn_readlane(my, j + 1);
            int s2 = __builtin_amdgcn_readlane(my, j + 2);
            int s3 = __builtin_amdgcn_readlane(my, j + 3);
            a += *(const float*)(pbase + (((size_t)(unsigned)s0) << 8) + voff);
            b += *(const float*)(pbase + (((size_t)(unsigned)s1) << 8) + voff);
            c += *(const float*)(pbase + (((size_t)(unsigned)s2) << 8) + voff);
            e += *(const float*)(pbase + (((size_t)(unsigned)s3) << 8) + voff);
        }
        for (; j < nb; ++j) {
            int s0 = __builtin_amdgcn_readlane(my, j);
            a += *(const float*)(pbase + (((size_t)(unsigned)s0) << 8) + voff);
        }
    }
    float inv = (d > 0) ? 1.0f / (float)d : 0.f;
    aggp[(long long)node * DOUT + lane] = (a + b + c + e) * inv;
}

// ---------------- MFMA GEMMs (unchanged) ----------------
#define LDSP 40

__global__ __launch_bounds__(256) void gemm1_mfma(
    const unsigned short* __restrict__ aggnb, const unsigned short* __restrict__ xb,
    const unsigned short* __restrict__ WT, const float* __restrict__ bias,
    unsigned short* __restrict__ h)
{
    __shared__ unsigned short Asm[128 * LDSP];
    __shared__ unsigned short Bsm[128 * LDSP];
    const int tid = threadIdx.x;
    const int bm = blockIdx.x * 128;
    const int bn = blockIdx.y * 128;
    const int wave = tid >> 6, lane = tid & 63;
    const int wr = wave >> 1, wc = wave & 1;
    const int lrow = lane & 15, quad = lane >> 4;

    f32x4 acc[4][4];
    #pragma unroll
    for (int i = 0; i < 4; ++i)
        #pragma unroll
        for (int j = 0; j < 4; ++j)
            acc[i][j] = (f32x4){0.f, 0.f, 0.f, 0.f};

    for (int k0 = 0; k0 < 256; k0 += 32) {
        #pragma unroll
        for (int c = tid; c < 512; c += 256) {
            int row = c >> 2, seg = c & 3;
            int grow = bm + row; if (grow >= NMID) grow = NMID - 1;
            int gk = k0 + seg * 8;
            const unsigned short* src = (gk < DIN)
                ? (aggnb + (long long)grow * DIN + gk)
                : (xb + (long long)grow * DIN + (gk - DIN));
            *(uint4*)(Asm + row * LDSP + seg * 8) = *(const uint4*)src;
        }
        #pragma unroll
        for (int c = tid; c < 512; c += 256) {
            int row = c >> 2, seg = c & 3;
            *(uint4*)(Bsm + row * LDSP + seg * 8) =
                *(const uint4*)(WT + (long long)(bn + row) * 256 + k0 + seg * 8);
        }
        __syncthreads();
        bf16x8 af[4], bfr[4];
        #pragma unroll
        for (int mi = 0; mi < 4; ++mi)
            af[mi] = *(const bf16x8*)(Asm + (wr * 64 + mi * 16 + lrow) * LDSP + quad * 8);
        #pragma unroll
        for (int ni = 0; ni < 4; ++ni)
            bfr[ni] = *(const bf16x8*)(Bsm + (wc * 64 + ni * 16 + lrow) * LDSP + quad * 8);
        #pragma unroll
        for (int mi = 0; mi < 4; ++mi)
            #pragma unroll
            for (int ni = 0; ni < 4; ++ni)
                acc[mi][ni] = __builtin_amdgcn_mfma_f32_16x16x32_bf16(
                    af[mi], bfr[ni], acc[mi][ni], 0, 0, 0);
        __syncthreads();
    }
    #pragma unroll
    for (int mi = 0; mi < 4; ++mi) {
        #pragma unroll
        for (int ni = 0; ni < 4; ++ni) {
            int col = bn + wc * 64 + ni * 16 + lrow;
            float bv = bias[col];
            #pragma unroll
            for (int r = 0; r < 4; ++r) {
                int row = bm + wr * 64 + mi * 16 + quad * 4 + r;
                if (row < NMID) {
                    float v = acc[mi][ni][r] + bv;
                    h[(long long)row * DHID + col] = f2bf(fmaxf(v, 0.0f));
                }
            }
        }
    }
}

template <bool FIN>
__global__ __launch_bounds__(256) void gemm_n64_mfma(
    const unsigned short* __restrict__ h, const unsigned short* __restrict__ WT,
    int nofs, int M,
    const float* __restrict__ bias, const float* __restrict__ aggp,
    float* __restrict__ outp)
{
    __shared__ unsigned short Asm[128 * LDSP];
    __shared__ unsigned short Bsm[64 * LDSP];
    const int tid = threadIdx.x;
    const int bm = blockIdx.x * 128;
    const int wave = tid >> 6, lane = tid & 63;
    const int lrow = lane & 15, quad = lane >> 4;

    f32x4 acc[2][4];
    #pragma unroll
    for (int i = 0; i < 2; ++i)
        #pragma unroll
        for (int j = 0; j < 4; ++j)
            acc[i][j] = (f32x4){0.f, 0.f, 0.f, 0.f};

    for (int k0 = 0; k0 < 256; k0 += 32) {
        #pragma unroll
        for (int c = tid; c < 512; c += 256) {
            int row = c >> 2, seg = c & 3;
            int grow = bm + row; if (grow >= M) grow = M - 1;
            *(uint4*)(Asm + row * LDSP + seg * 8) =
                *(const uint4*)(h + (long long)grow * DHID + k0 + seg * 8);
        }
        {
            int row = tid >> 2, seg = tid & 3;
            *(uint4*)(Bsm + row * LDSP + seg * 8) =
                *(const uint4*)(WT + (long long)(nofs + row) * 256 + k0 + seg * 8);
        }
        __syncthreads();
        bf16x8 af[2], bfr[4];
        #pragma unroll
        for (int mi = 0; mi < 2; ++mi)
            af[mi] = *(const bf16x8*)(Asm + (wave * 32 + mi * 16 + lrow) * LDSP + quad * 8);
        #pragma unroll
        for (int ni = 0; ni < 4; ++ni)
            bfr[ni] = *(const bf16x8*)(Bsm + (ni * 16 + lrow) * LDSP + quad * 8);
        #pragma unroll
        for (int mi = 0; mi < 2; ++mi)
            #pragma unroll
            for (int ni = 0; ni < 4; ++ni)
                acc[mi][ni] = __builtin_amdgcn_mfma_f32_16x16x32_bf16(
                    af[mi], bfr[ni], acc[mi][ni], 0, 0, 0);
        __syncthreads();
    }
    #pragma unroll
    for (int mi = 0; mi < 2; ++mi) {
        #pragma unroll
        for (int ni = 0; ni < 4; ++ni) {
            int col = ni * 16 + lrow;
            float bv = FIN ? bias[col] : 0.f;
            #pragma unroll
            for (int r = 0; r < 4; ++r) {
                int row = bm + wave * 32 + mi * 16 + quad * 4 + r;
                if (row < M) {
                    float v = acc[mi][ni][r] + bv;
                    if (FIN) v += aggp[(long long)row * DOUT + col];
                    outp[(long long)row * DOUT + col] = v;
                }
            }
        }
    }
}

extern "C" void kernel_launch(void* const* d_in, const int* in_sizes, int n_in,
                              void* d_out, int out_size, void* d_ws, size_t ws_size,
                              hipStream_t stream) {
    const float* x   = (const float*)d_in[0];
    const int*   ei1 = (const int*)d_in[1];
    const int*   ei2 = (const int*)d_in[2];
    const float* Wl1 = (const float*)d_in[3];
    const float* Wr1 = (const float*)d_in[4];
    const float* b1  = (const float*)d_in[5];
    const float* Wl2 = (const float*)d_in[6];
    const float* Wr2 = (const float*)d_in[7];
    const float* b2  = (const float*)d_in[8];
    float* out = (float*)d_out;

    unsigned short* xb    = (unsigned short*)d_ws;
    unsigned short* aggnb = xb + (size_t)NSRC * DIN;
    unsigned short* h     = aggnb + (size_t)NMID * DIN;
    unsigned short* WT1   = h + (size_t)NMID * DHID;
    unsigned short* WT2   = WT1 + 256 * 256;
    float* p    = (float*)(WT2 + 128 * 256);
    float* aggp = p + (size_t)NMID * DOUT;
    int* cnt1  = (int*)(aggp + (size_t)NTGT * DOUT);
    int* cnt2  = cnt1 + NMID;
    int* rs1   = cnt2 + NTGT;
    int* rs2   = rs1 + (NMID + 1);
    int* bsum1 = rs2 + (NTGT + 1);
    int* bsum2 = bsum1 + 256;
    int* csr1  = bsum2 + 256;
    int* csr2  = csr1 + NE1;

    // converts (independent)
    convert_all_kernel<<<(XCH + 65536 + 32768 + 255) / 256, 256, 0, stream>>>(
        x, Wl1, Wr1, Wl2, Wr2, xb, WT1, WT2);

    // CSR build, both layers
    hipMemsetAsync(cnt1, 0, (size_t)(NMID + NTGT) * 4, stream);
    hist_both_kernel<<<(NE1 + NE2 + 255) / 256, 256, 0, stream>>>(ei1, ei2, cnt1, cnt2);
    scan_reduce_both_kernel<<<NB1 + NB2, 256, 0, stream>>>(cnt1, cnt2, bsum1, bsum2);
    scan_top_both_kernel<<<1, 256, 0, stream>>>(bsum1, bsum2, rs1, rs2);
    scan_apply_both_kernel<<<NB1 + NB2, 256, 0, stream>>>(cnt1, cnt2, bsum1, bsum2, rs1, rs2);
    fill_both_kernel<<<(NE1 + NE2 + 255) / 256, 256, 0, stream>>>(
        ei1, ei2, rs1, rs2, cnt1, cnt2, csr1, csr2);

    // layer 1
    gather1_kernel<<<(NMID + 3) / 4, 256, 0, stream>>>(xb, rs1, csr1, aggnb);
    {
        dim3 grid((NMID + 127) / 128, 2);
        gemm1_mfma<<<grid, 256, 0, stream>>>(aggnb, xb, WT1, b1, h);
    }
    // layer 2
    gemm_n64_mfma<false><<<(NMID + 127) / 128, 256, 0, stream>>>(
        h, WT2, 0, NMID, nullptr, nullptr, p);
    gather2_kernel<<<(NTGT + 3) / 4, 256, 0, stream>>>(p, rs2, csr2, aggp);
    gemm_n64_mfma<true><<<(NTGT + 127) / 128, 256, 0, stream>>>(
        h, WT2, 64, NTGT, b2, aggp, out);
}

// Round 5
// 556.920 us; speedup vs baseline: 6.9140x; 1.0373x over previous
//
#include <hip/hip_runtime.h>

// GraphSAGE 2-layer. Round 5: bucket-binned CSR fill (kills the 163MB write
// amplification of scattered dword stores). Gathers/GEMMs from round 4.

#define NSRC 200000
#define NMID 100000
#define NTGT 50000
#define NE1  1600000
#define NE2  800000
#define DIN  128
#define DHID 256
#define DOUT 64

#define NB1 98   // (NMID+1023)/1024 scan blocks
#define NB2 49
#define XCH (NSRC * 16)

#define CH   4096                 // edges per binning workgroup
#define NBK1 391                  // (NMID+255)/256
#define NBK2 196                  // (NTGT+255)/256
#define NCH1 ((NE1 + CH - 1) / CH)   // 391
#define NCH2 ((NE2 + CH - 1) / CH)   // 196

typedef __attribute__((ext_vector_type(8))) short bf16x8;
typedef __attribute__((ext_vector_type(4))) float f32x4;

__device__ __forceinline__ unsigned short f2bf(float f) {
    unsigned int u = __builtin_bit_cast(unsigned int, f);
    u += 0x7FFFu + ((u >> 16) & 1u);
    return (unsigned short)(u >> 16);
}
__device__ __forceinline__ float bf_lo(unsigned int u) {
    return __builtin_bit_cast(float, u << 16);
}
__device__ __forceinline__ float bf_hi(unsigned int u) {
    return __builtin_bit_cast(float, u & 0xFFFF0000u);
}

// ---------------- fused converts ----------------
__global__ __launch_bounds__(256) void convert_all_kernel(
    const float* __restrict__ x,
    const float* __restrict__ Wl1, const float* __restrict__ Wr1,
    const float* __restrict__ Wl2, const float* __restrict__ Wr2,
    unsigned short* __restrict__ xb, unsigned short* __restrict__ WT1,
    unsigned short* __restrict__ WT2)
{
    int gid = blockIdx.x * 256 + threadIdx.x;
    if (gid < XCH) {
        const float4 v0 = *(const float4*)(x + (long long)gid * 8);
        const float4 v1 = *(const float4*)(x + (long long)gid * 8 + 4);
        unsigned short o[8] = {f2bf(v0.x), f2bf(v0.y), f2bf(v0.z), f2bf(v0.w),
                               f2bf(v1.x), f2bf(v1.y), f2bf(v1.z), f2bf(v1.w)};
        *(uint4*)(xb + (long long)gid * 8) = *(const uint4*)o;
        return;
    }
    int g = gid - XCH;
    if (g < 65536) {
        int n = g >> 8, k = g & 255;
        float v = (k < DIN) ? Wl1[(long long)k * DHID + n]
                            : Wr1[(long long)(k - DIN) * DHID + n];
        WT1[g] = f2bf(v);
        return;
    }
    g -= 65536;
    if (g < 32768) {
        int n2 = g >> 8, k = g & 255;
        float v = (n2 < DOUT) ? Wl2[(long long)k * DOUT + n2]
                              : Wr2[(long long)k * DOUT + (n2 - DOUT)];
        WT2[g] = f2bf(v);
    }
}

// ---------------- CSR build ----------------

__global__ __launch_bounds__(256) void hist_both_kernel(
    const int* __restrict__ ei1, const int* __restrict__ ei2,
    int* __restrict__ cnt1, int* __restrict__ cnt2)
{
    int e = blockIdx.x * 256 + threadIdx.x;
    if (e < NE1) { atomicAdd(&cnt1[ei1[NE1 + e]], 1); return; }
    e -= NE1;
    if (e < NE2) atomicAdd(&cnt2[ei2[NE2 + e]], 1);
}

__global__ __launch_bounds__(256) void scan_reduce_both_kernel(
    const int* __restrict__ cnt1, const int* __restrict__ cnt2,
    int* __restrict__ bsum1, int* __restrict__ bsum2)
{
    const int* cnt; int* bsum; int n, bi;
    if (blockIdx.x < NB1) { cnt = cnt1; bsum = bsum1; n = NMID; bi = blockIdx.x; }
    else { cnt = cnt2; bsum = bsum2; n = NTGT; bi = blockIdx.x - NB1; }
    __shared__ int sdata[256];
    int base = bi * 1024;
    int t = threadIdx.x;
    int s = 0;
    #pragma unroll
    for (int i = 0; i < 4; ++i) {
        int idx = base + t * 4 + i;
        s += (idx < n) ? cnt[idx] : 0;
    }
    sdata[t] = s; __syncthreads();
    for (int off = 128; off > 0; off >>= 1) {
        if (t < off) sdata[t] += sdata[t + off];
        __syncthreads();
    }
    if (t == 0) bsum[bi] = sdata[0];
}

__global__ __launch_bounds__(256) void scan_top_both_kernel(
    int* __restrict__ bsum1, int* __restrict__ bsum2,
    int* __restrict__ rs1, int* __restrict__ rs2)
{
    __shared__ int sm[256];
    int t = threadIdx.x;
    sm[t] = (t < NB1) ? bsum1[t] : 0;
    __syncthreads();
    for (int off = 1; off < 256; off <<= 1) {
        int v = (t >= off) ? sm[t - off] : 0;
        __syncthreads();
        sm[t] += v;
        __syncthreads();
    }
    if (t < NB1) bsum1[t] = (t == 0) ? 0 : sm[t - 1];
    __syncthreads();
    sm[t] = (t < NB2) ? bsum2[t] : 0;
    __syncthreads();
    for (int off = 1; off < 256; off <<= 1) {
        int v = (t >= off) ? sm[t - off] : 0;
        __syncthreads();
        sm[t] += v;
        __syncthreads();
    }
    if (t < NB2) bsum2[t] = (t == 0) ? 0 : sm[t - 1];
    if (t == 0) { rs1[NMID] = NE1; rs2[NTGT] = NE2; }
}

__global__ __launch_bounds__(256) void scan_apply_both_kernel(
    const int* __restrict__ cnt1, const int* __restrict__ cnt2,
    const int* __restrict__ bsum1, const int* __restrict__ bsum2,
    int* __restrict__ rs1, int* __restrict__ rs2)
{
    const int* cnt; const int* bsum; int* rs; int n, bi;
    if (blockIdx.x < NB1) { cnt = cnt1; bsum = bsum1; rs = rs1; n = NMID; bi = blockIdx.x; }
    else { cnt = cnt2; bsum = bsum2; rs = rs2; n = NTGT; bi = blockIdx.x - NB1; }
    __shared__ int s[256];
    int base = bi * 1024;
    int t = threadIdx.x;
    int idx0 = base + t * 4;
    int v[4]; int sum = 0;
    #pragma unroll
    for (int i = 0; i < 4; ++i) {
        int id = idx0 + i;
        v[i] = (id < n) ? cnt[id] : 0;
        sum += v[i];
    }
    s[t] = sum; __syncthreads();
    for (int off = 1; off < 256; off <<= 1) {
        int u = (t >= off) ? s[t - off] : 0;
        __syncthreads();
        s[t] += u;
        __syncthreads();
    }
    int run = bsum[bi] + ((t == 0) ? 0 : s[t - 1]);
    #pragma unroll
    for (int i = 0; i < 4; ++i) {
        int id = idx0 + i;
        if (id < n) rs[id] = run;
        run += v[i];
    }
}

// bucket cursors start at rs[bucket*256]
__global__ __launch_bounds__(256) void init_bcur_kernel(
    const int* __restrict__ rs1, const int* __restrict__ rs2,
    int* __restrict__ bcur1, int* __restrict__ bcur2)
{
    int t = blockIdx.x * 256 + threadIdx.x;
    if (t < NBK1) { bcur1[t] = rs1[t * 256]; return; }
    t -= NBK1;
    if (t < NBK2) bcur2[t] = rs2[t * 256];
}

// bin edges into bucket-contiguous record array (src,tgt), LDS-staged so
// global writes are ~line-granular runs instead of random dwords.
__global__ __launch_bounds__(256) void bin_kernel(
    const int* __restrict__ ei1, const int* __restrict__ ei2,
    int* __restrict__ bcur1, int* __restrict__ bcur2,
    uint2* __restrict__ gbuf1, uint2* __restrict__ gbuf2)
{
    __shared__ unsigned int lcnt[512];
    __shared__ unsigned int lofs[512];
    __shared__ unsigned int lpos[512];
    __shared__ unsigned int gbase[512];
    __shared__ unsigned int swarp[256];
    __shared__ uint2 lbuf[CH];

    const int* ei; int* bcur; uint2* gbuf; int nE, nbk, chunk;
    if (blockIdx.x < NCH1) {
        ei = ei1; bcur = bcur1; gbuf = gbuf1; nE = NE1; nbk = NBK1; chunk = blockIdx.x;
    } else {
        ei = ei2; bcur = bcur2; gbuf = gbuf2; nE = NE2; nbk = NBK2; chunk = blockIdx.x - NCH1;
    }
    int base = chunk * CH;
    int nb = nE - base; if (nb > CH) nb = CH;
    int t = threadIdx.x;

    for (int i = t; i < 512; i += 256) { lcnt[i] = 0; lpos[i] = 0; }
    __syncthreads();

    int srcv[16], tgtv[16];
    #pragma unroll
    for (int i = 0; i < 16; ++i) {
        int e = base + i * 256 + t;
        if (e < nE) {
            tgtv[i] = ei[nE + e];
            srcv[i] = ei[e];
            atomicAdd(&lcnt[tgtv[i] >> 8], 1u);
        } else tgtv[i] = -1;
    }
    __syncthreads();

    // exclusive scan of lcnt[0..512) -> lofs (2 entries per thread)
    unsigned a0 = lcnt[2 * t], a1 = lcnt[2 * t + 1];
    swarp[t] = a0 + a1;
    __syncthreads();
    for (int off = 1; off < 256; off <<= 1) {
        unsigned v = (t >= off) ? swarp[t - off] : 0;
        __syncthreads();
        swarp[t] += v;
        __syncthreads();
    }
    unsigned ex = (t > 0) ? swarp[t - 1] : 0;
    lofs[2 * t] = ex;
    lofs[2 * t + 1] = ex + a0;
    // reserve global space for this chunk's bucket groups
    if (2 * t < nbk && a0) gbase[2 * t] = atomicAdd(&bcur[2 * t], (int)a0);
    if (2 * t + 1 < nbk && a1) gbase[2 * t + 1] = atomicAdd(&bcur[2 * t + 1], (int)a1);
    __syncthreads();

    // place records grouped by bucket
    #pragma unroll
    for (int i = 0; i < 16; ++i) {
        if (tgtv[i] >= 0) {
            int b = tgtv[i] >> 8;
            unsigned idx = lofs[b] + atomicAdd(&lpos[b], 1u);
            lbuf[idx] = make_uint2((unsigned)srcv[i], (unsigned)tgtv[i]);
        }
    }
    __syncthreads();

    // copy out: contiguous within each bucket group
    for (int i = t; i < nb; i += 256) {
        uint2 r = lbuf[i];
        int b = (int)(r.y >> 8);
        unsigned gi = gbase[b] + ((unsigned)i - lofs[b]);
        gbuf[gi] = r;
    }
}

// fill csr from bucket-sorted records: writes now confined to small L2-resident windows
__global__ __launch_bounds__(256) void fill_csr_kernel(
    const uint2* __restrict__ gbuf1, const uint2* __restrict__ gbuf2,
    const int* __restrict__ rs1, const int* __restrict__ rs2,
    int* __restrict__ cnt1, int* __restrict__ cnt2,
    int* __restrict__ csr1, int* __restrict__ csr2)
{
    int e = blockIdx.x * 256 + threadIdx.x;
    const uint2* g; const int* rs; int* cnt; int* csr;
    if (e < NE1) { g = gbuf1; rs = rs1; cnt = cnt1; csr = csr1; }
    else {
        e -= NE1;
        if (e >= NE2) return;
        g = gbuf2; rs = rs2; cnt = cnt2; csr = csr2;
    }
    uint2 r = g[e];
    int tgt = (int)r.y;
    int pos = atomicSub(&cnt[tgt], 1) - 1;
    csr[rs[tgt] + pos] = (int)r.x;
}

// ---------------- gathers (round 4 readlane version) ----------------

__global__ __launch_bounds__(256) void gather1_kernel(
    const unsigned short* __restrict__ xb, const int* __restrict__ rs,
    const int* __restrict__ csr, unsigned short* __restrict__ aggnb)
{
    int node = blockIdx.x * 4 + (threadIdx.x >> 6);
    if (node >= NMID) return;
    int lane = threadIdx.x & 63;
    int s = rs[node];
    int d = rs[node + 1] - s;
    const char* xbase = (const char*)xb;
    unsigned int voff = (unsigned int)lane * 4u;
    float a0 = 0.f, a1 = 0.f, b0 = 0.f, b1 = 0.f;
    float c0 = 0.f, c1 = 0.f, e0 = 0.f, e1 = 0.f;
    for (int base = 0; base < d; base += 64) {
        int nb = d - base; if (nb > 64) nb = 64;
        int li = base + lane; if (li > d - 1) li = d - 1;
        int my = csr[s + li];
        int j = 0;
        for (; j + 3 < nb; j += 4) {
            int s0 = __builtin_amdgcn_readlane(my, j);
            int s1 = __builtin_amdgcn_readlane(my, j + 1);
            int s2 = __builtin_amdgcn_readlane(my, j + 2);
            int s3 = __builtin_amdgcn_readlane(my, j + 3);
            unsigned int u0 = *(const unsigned int*)(xbase + (((size_t)(unsigned)s0) << 8) + voff);
            unsigned int u1 = *(const unsigned int*)(xbase + (((size_t)(unsigned)s1) << 8) + voff);
            unsigned int u2 = *(const unsigned int*)(xbase + (((size_t)(unsigned)s2) << 8) + voff);
            unsigned int u3 = *(const unsigned int*)(xbase + (((size_t)(unsigned)s3) << 8) + voff);
            a0 += bf_lo(u0); a1 += bf_hi(u0);
            b0 += bf_lo(u1); b1 += bf_hi(u1);
            c0 += bf_lo(u2); c1 += bf_hi(u2);
            e0 += bf_lo(u3); e1 += bf_hi(u3);
        }
        for (; j < nb; ++j) {
            int s0 = __builtin_amdgcn_readlane(my, j);
            unsigned int u0 = *(const unsigned int*)(xbase + (((size_t)(unsigned)s0) << 8) + voff);
            a0 += bf_lo(u0); a1 += bf_hi(u0);
        }
    }
    float inv = (d > 0) ? 1.0f / (float)d : 0.f;
    float r0 = (a0 + b0 + c0 + e0) * inv;
    float r1 = (a1 + b1 + c1 + e1) * inv;
    unsigned int packed = (unsigned int)f2bf(r0) | ((unsigned int)f2bf(r1) << 16);
    *(unsigned int*)(aggnb + (long long)node * DIN + lane * 2) = packed;
}

__global__ __launch_bounds__(256) void gather2_kernel(
    const float* __restrict__ p, const int* __restrict__ rs,
    const int* __restrict__ csr, float* __restrict__ aggp)
{
    int node = blockIdx.x * 4 + (threadIdx.x >> 6);
    if (node >= NTGT) return;
    int lane = threadIdx.x & 63;
    int s = rs[node];
    int d = rs[node + 1] - s;
    const char* pbase = (const char*)p;
    unsigned int voff = (unsigned int)lane * 4u;
    float a = 0.f, b = 0.f, c = 0.f, e = 0.f;
    for (int base = 0; base < d; base += 64) {
        int nb = d - base; if (nb > 64) nb = 64;
        int li = base + lane; if (li > d - 1) li = d - 1;
        int my = csr[s + li];
        int j = 0;
        for (; j + 3 < nb; j += 4) {
            int s0 = __builtin_amdgcn_readlane(my, j);
            int s1 = __builtin_amdgcn_readlane(my, j + 1);
            int s2 = __builtin_amdgcn_readlane(my, j + 2);
            int s3 = __builtin_amdgcn_readlane(my, j + 3);
            a += *(const float*)(pbase + (((size_t)(unsigned)s0) << 8) + voff);
            b += *(const float*)(pbase + (((size_t)(unsigned)s1) << 8) + voff);
            c += *(const float*)(pbase + (((size_t)(unsigned)s2) << 8) + voff);
            e += *(const float*)(pbase + (((size_t)(unsigned)s3) << 8) + voff);
        }
        for (; j < nb; ++j) {
            int s0 = __builtin_amdgcn_readlane(my, j);
            a += *(const float*)(pbase + (((size_t)(unsigned)s0) << 8) + voff);
        }
    }
    float inv = (d > 0) ? 1.0f / (float)d : 0.f;
    aggp[(long long)node * DOUT + lane] = (a + b + c + e) * inv;
}

// ---------------- MFMA GEMMs ----------------
#define LDSP 40

__global__ __launch_bounds__(256) void gemm1_mfma(
    const unsigned short* __restrict__ aggnb, const unsigned short* __restrict__ xb,
    const unsigned short* __restrict__ WT, const float* __restrict__ bias,
    unsigned short* __restrict__ h)
{
    __shared__ unsigned short Asm[128 * LDSP];
    __shared__ unsigned short Bsm[128 * LDSP];
    const int tid = threadIdx.x;
    const int bm = blockIdx.x * 128;
    const int bn = blockIdx.y * 128;
    const int wave = tid >> 6, lane = tid & 63;
    const int wr = wave >> 1, wc = wave & 1;
    const int lrow = lane & 15, quad = lane >> 4;

    f32x4 acc[4][4];
    #pragma unroll
    for (int i = 0; i < 4; ++i)
        #pragma unroll
        for (int j = 0; j < 4; ++j)
            acc[i][j] = (f32x4){0.f, 0.f, 0.f, 0.f};

    for (int k0 = 0; k0 < 256; k0 += 32) {
        #pragma unroll
        for (int c = tid; c < 512; c += 256) {
            int row = c >> 2, seg = c & 3;
            int grow = bm + row; if (grow >= NMID) grow = NMID - 1;
            int gk = k0 + seg * 8;
            const unsigned short* src = (gk < DIN)
                ? (aggnb + (long long)grow * DIN + gk)
                : (xb + (long long)grow * DIN + (gk - DIN));
            *(uint4*)(Asm + row * LDSP + seg * 8) = *(const uint4*)src;
        }
        #pragma unroll
        for (int c = tid; c < 512; c += 256) {
            int row = c >> 2, seg = c & 3;
            *(uint4*)(Bsm + row * LDSP + seg * 8) =
                *(const uint4*)(WT + (long long)(bn + row) * 256 + k0 + seg * 8);
        }
        __syncthreads();
        bf16x8 af[4], bfr[4];
        #pragma unroll
        for (int mi = 0; mi < 4; ++mi)
            af[mi] = *(const bf16x8*)(Asm + (wr * 64 + mi * 16 + lrow) * LDSP + quad * 8);
        #pragma unroll
        for (int ni = 0; ni < 4; ++ni)
            bfr[ni] = *(const bf16x8*)(Bsm + (wc * 64 + ni * 16 + lrow) * LDSP + quad * 8);
        #pragma unroll
        for (int mi = 0; mi < 4; ++mi)
            #pragma unroll
            for (int ni = 0; ni < 4; ++ni)
                acc[mi][ni] = __builtin_amdgcn_mfma_f32_16x16x32_bf16(
                    af[mi], bfr[ni], acc[mi][ni], 0, 0, 0);
        __syncthreads();
    }
    #pragma unroll
    for (int mi = 0; mi < 4; ++mi) {
        #pragma unroll
        for (int ni = 0; ni < 4; ++ni) {
            int col = bn + wc * 64 + ni * 16 + lrow;
            float bv = bias[col];
            #pragma unroll
            for (int r = 0; r < 4; ++r) {
                int row = bm + wr * 64 + mi * 16 + quad * 4 + r;
                if (row < NMID) {
                    float v = acc[mi][ni][r] + bv;
                    h[(long long)row * DHID + col] = f2bf(fmaxf(v, 0.0f));
                }
            }
        }
    }
}

template <bool FIN>
__global__ __launch_bounds__(256) void gemm_n64_mfma(
    const unsigned short* __restrict__ h, const unsigned short* __restrict__ WT,
    int nofs, int M,
    const float* __restrict__ bias, const float* __restrict__ aggp,
    float* __restrict__ outp)
{
    __shared__ unsigned short Asm[128 * LDSP];
    __shared__ unsigned short Bsm[64 * LDSP];
    const int tid = threadIdx.x;
    const int bm = blockIdx.x * 128;
    const int wave = tid >> 6, lane = tid & 63;
    const int lrow = lane & 15, quad = lane >> 4;

    f32x4 acc[2][4];
    #pragma unroll
    for (int i = 0; i < 2; ++i)
        #pragma unroll
        for (int j = 0; j < 4; ++j)
            acc[i][j] = (f32x4){0.f, 0.f, 0.f, 0.f};

    for (int k0 = 0; k0 < 256; k0 += 32) {
        #pragma unroll
        for (int c = tid; c < 512; c += 256) {
            int row = c >> 2, seg = c & 3;
            int grow = bm + row; if (grow >= M) grow = M - 1;
            *(uint4*)(Asm + row * LDSP + seg * 8) =
                *(const uint4*)(h + (long long)grow * DHID + k0 + seg * 8);
        }
        {
            int row = tid >> 2, seg = tid & 3;
            *(uint4*)(Bsm + row * LDSP + seg * 8) =
                *(const uint4*)(WT + (long long)(nofs + row) * 256 + k0 + seg * 8);
        }
        __syncthreads();
        bf16x8 af[2], bfr[4];
        #pragma unroll
        for (int mi = 0; mi < 2; ++mi)
            af[mi] = *(const bf16x8*)(Asm + (wave * 32 + mi * 16 + lrow) * LDSP + quad * 8);
        #pragma unroll
        for (int ni = 0; ni < 4; ++ni)
            bfr[ni] = *(const bf16x8*)(Bsm + (ni * 16 + lrow) * LDSP + quad * 8);
        #pragma unroll
        for (int mi = 0; mi < 2; ++mi)
            #pragma unroll
            for (int ni = 0; ni < 4; ++ni)
                acc[mi][ni] = __builtin_amdgcn_mfma_f32_16x16x32_bf16(
                    af[mi], bfr[ni], acc[mi][ni], 0, 0, 0);
        __syncthreads();
    }
    #pragma unroll
    for (int mi = 0; mi < 2; ++mi) {
        #pragma unroll
        for (int ni = 0; ni < 4; ++ni) {
            int col = ni * 16 + lrow;
            float bv = FIN ? bias[col] : 0.f;
            #pragma unroll
            for (int r = 0; r < 4; ++r) {
                int row = bm + wave * 32 + mi * 16 + quad * 4 + r;
                if (row < M) {
                    float v = acc[mi][ni][r] + bv;
                    if (FIN) v += aggp[(long long)row * DOUT + col];
                    outp[(long long)row * DOUT + col] = v;
                }
            }
        }
    }
}

extern "C" void kernel_launch(void* const* d_in, const int* in_sizes, int n_in,
                              void* d_out, int out_size, void* d_ws, size_t ws_size,
                              hipStream_t stream) {
    const float* x   = (const float*)d_in[0];
    const int*   ei1 = (const int*)d_in[1];
    const int*   ei2 = (const int*)d_in[2];
    const float* Wl1 = (const float*)d_in[3];
    const float* Wr1 = (const float*)d_in[4];
    const float* b1  = (const float*)d_in[5];
    const float* Wl2 = (const float*)d_in[6];
    const float* Wr2 = (const float*)d_in[7];
    const float* b2  = (const float*)d_in[8];
    float* out = (float*)d_out;

    unsigned short* xb    = (unsigned short*)d_ws;
    unsigned short* aggnb = xb + (size_t)NSRC * DIN;
    unsigned short* h     = aggnb + (size_t)NMID * DIN;
    unsigned short* WT1   = h + (size_t)NMID * DHID;
    unsigned short* WT2   = WT1 + 256 * 256;
    float* p    = (float*)(WT2 + 128 * 256);
    float* aggp = p + (size_t)NMID * DOUT;
    int* cnt1  = (int*)(aggp + (size_t)NTGT * DOUT);
    int* cnt2  = cnt1 + NMID;
    int* rs1   = cnt2 + NTGT;
    int* rs2   = rs1 + (NMID + 1);
    int* bsum1 = rs2 + (NTGT + 1);
    int* bsum2 = bsum1 + 256;
    int* bcur1 = bsum2 + 256;
    int* bcur2 = bcur1 + NBK1;
    int* csr1  = bcur2 + NBK2 + 1;
    int* csr2  = csr1 + NE1;
    uint2* gbuf1 = (uint2*)(((size_t)(csr2 + NE2) + 15) & ~(size_t)15);
    uint2* gbuf2 = gbuf1 + NE1;

    convert_all_kernel<<<(XCH + 65536 + 32768 + 255) / 256, 256, 0, stream>>>(
        x, Wl1, Wr1, Wl2, Wr2, xb, WT1, WT2);

    hipMemsetAsync(cnt1, 0, (size_t)(NMID + NTGT) * 4, stream);
    hist_both_kernel<<<(NE1 + NE2 + 255) / 256, 256, 0, stream>>>(ei1, ei2, cnt1, cnt2);
    scan_reduce_both_kernel<<<NB1 + NB2, 256, 0, stream>>>(cnt1, cnt2, bsum1, bsum2);
    scan_top_both_kernel<<<1, 256, 0, stream>>>(bsum1, bsum2, rs1, rs2);
    scan_apply_both_kernel<<<NB1 + NB2, 256, 0, stream>>>(cnt1, cnt2, bsum1, bsum2, rs1, rs2);
    init_bcur_kernel<<<3, 256, 0, stream>>>(rs1, rs2, bcur1, bcur2);
    bin_kernel<<<NCH1 + NCH2, 256, 0, stream>>>(ei1, ei2, bcur1, bcur2, gbuf1, gbuf2);
    fill_csr_kernel<<<(NE1 + NE2 + 255) / 256, 256, 0, stream>>>(
        gbuf1, gbuf2, rs1, rs2, cnt1, cnt2, csr1, csr2);

    gather1_kernel<<<(NMID + 3) / 4, 256, 0, stream>>>(xb, rs1, csr1, aggnb);
    {
        dim3 grid((NMID + 127) / 128, 2);
        gemm1_mfma<<<grid, 256, 0, stream>>>(aggnb, xb, WT1, b1, h);
    }
    gemm_n64_mfma<false><<<(NMID + 127) / 128, 256, 0, stream>>>(
        h, WT2, 0, NMID, nullptr, nullptr, p);
    gather2_kernel<<<(NTGT + 3) / 4, 256, 0, stream>>>(p, rs2, csr2, aggp);
    gemm_n64_mfma<true><<<(NTGT + 127) / 128, 256, 0, stream>>>(
        h, WT2, 64, NTGT, b2, aggp, out);
}

// Round 6
// 433.609 us; speedup vs baseline: 8.8802x; 1.2844x over previous
//
#include <hip/hip_runtime.h>

// GraphSAGE 2-layer. Round 6: bucket-first CSR build — LDS-aggregated bucket
// histogram (replaces 2.4M global atomics), per-bucket CSR construction with
// fully coalesced rs/csr writes. Gathers/GEMMs/bin from round 5.

#define NSRC 200000
#define NMID 100000
#define NTGT 50000
#define NE1  1600000
#define NE2  800000
#define DIN  128
#define DHID 256
#define DOUT 64

#define XCH (NSRC * 16)

#define CH   4096                    // edges per binning workgroup
#define NBK1 391                     // (NMID+255)/256 buckets
#define NBK2 196                     // (NTGT+255)/256
#define NCH1 ((NE1 + CH - 1) / CH)   // 391
#define NCH2 ((NE2 + CH - 1) / CH)   // 196
#define HCH  8192                    // edges per hist block
#define NHC1 ((NE1 + HCH - 1) / HCH) // 196
#define NHC2 ((NE2 + HCH - 1) / HCH) // 98
#define MAXBUF 6144                  // >= max bucket size (mean 4096, std 64)

typedef __attribute__((ext_vector_type(8))) short bf16x8;
typedef __attribute__((ext_vector_type(4))) float f32x4;

__device__ __forceinline__ unsigned short f2bf(float f) {
    unsigned int u = __builtin_bit_cast(unsigned int, f);
    u += 0x7FFFu + ((u >> 16) & 1u);
    return (unsigned short)(u >> 16);
}
__device__ __forceinline__ float bf_lo(unsigned int u) {
    return __builtin_bit_cast(float, u << 16);
}
__device__ __forceinline__ float bf_hi(unsigned int u) {
    return __builtin_bit_cast(float, u & 0xFFFF0000u);
}

// ---------------- fused converts ----------------
__global__ __launch_bounds__(256) void convert_all_kernel(
    const float* __restrict__ x,
    const float* __restrict__ Wl1, const float* __restrict__ Wr1,
    const float* __restrict__ Wl2, const float* __restrict__ Wr2,
    unsigned short* __restrict__ xb, unsigned short* __restrict__ WT1,
    unsigned short* __restrict__ WT2)
{
    int gid = blockIdx.x * 256 + threadIdx.x;
    if (gid < XCH) {
        const float4 v0 = *(const float4*)(x + (long long)gid * 8);
        const float4 v1 = *(const float4*)(x + (long long)gid * 8 + 4);
        unsigned short o[8] = {f2bf(v0.x), f2bf(v0.y), f2bf(v0.z), f2bf(v0.w),
                               f2bf(v1.x), f2bf(v1.y), f2bf(v1.z), f2bf(v1.w)};
        *(uint4*)(xb + (long long)gid * 8) = *(const uint4*)o;
        return;
    }
    int g = gid - XCH;
    if (g < 65536) {
        int n = g >> 8, k = g & 255;
        float v = (k < DIN) ? Wl1[(long long)k * DHID + n]
                            : Wr1[(long long)(k - DIN) * DHID + n];
        WT1[g] = f2bf(v);
        return;
    }
    g -= 65536;
    if (g < 32768) {
        int n2 = g >> 8, k = g & 255;
        float v = (n2 < DOUT) ? Wl2[(long long)k * DOUT + n2]
                              : Wr2[(long long)k * DOUT + (n2 - DOUT)];
        WT2[g] = f2bf(v);
    }
}

// ---------------- bucket-first CSR build ----------------

// LDS-aggregated histogram over buckets (tgt >> 8)
__global__ __launch_bounds__(256) void bucket_hist_kernel(
    const int* __restrict__ ei1, const int* __restrict__ ei2,
    int* __restrict__ bhist1, int* __restrict__ bhist2)
{
    __shared__ unsigned int lh[512];
    const int* ei; int* bh; int nE, nbk, chunk;
    if (blockIdx.x < NHC1) { ei = ei1; bh = bhist1; nE = NE1; nbk = NBK1; chunk = blockIdx.x; }
    else { ei = ei2; bh = bhist2; nE = NE2; nbk = NBK2; chunk = blockIdx.x - NHC1; }
    int t = threadIdx.x;
    lh[t] = 0; lh[t + 256] = 0;
    __syncthreads();
    int base = chunk * HCH;
    int end = nE < base + HCH ? nE : base + HCH;
    for (int e = base + t; e < end; e += 256)
        atomicAdd(&lh[((unsigned)ei[nE + e]) >> 8], 1u);
    __syncthreads();
    if (t < nbk && lh[t]) atomicAdd(&bh[t], (int)lh[t]);
    if (t + 256 < nbk && lh[t + 256]) atomicAdd(&bh[t + 256], (int)lh[t + 256]);
}

// single block: exclusive scan of bucket totals -> bases + cursors; set rs tails
__global__ __launch_bounds__(256) void bucket_scan_kernel(
    const int* __restrict__ bhist1, const int* __restrict__ bhist2,
    int* __restrict__ bbase1, int* __restrict__ bbase2,
    int* __restrict__ bcur1, int* __restrict__ bcur2,
    int* __restrict__ rs1, int* __restrict__ rs2)
{
    __shared__ int s[256];
    int t = threadIdx.x;
    // layer 1: NBK1=391, 2 entries/thread
    int a0 = (2 * t < NBK1) ? bhist1[2 * t] : 0;
    int a1 = (2 * t + 1 < NBK1) ? bhist1[2 * t + 1] : 0;
    s[t] = a0 + a1;
    __syncthreads();
    for (int off = 1; off < 256; off <<= 1) {
        int u = (t >= off) ? s[t - off] : 0;
        __syncthreads();
        s[t] += u;
        __syncthreads();
    }
    int ex = (t > 0) ? s[t - 1] : 0;
    if (2 * t < NBK1)     { bbase1[2 * t] = ex;      bcur1[2 * t] = ex; }
    if (2 * t + 1 < NBK1) { bbase1[2 * t + 1] = ex + a0; bcur1[2 * t + 1] = ex + a0; }
    if (t == 0) { bbase1[NBK1] = NE1; rs1[NMID] = NE1; bbase2[NBK2] = NE2; rs2[NTGT] = NE2; }
    __syncthreads();
    // layer 2: NBK2=196, 1 entry/thread
    int b0 = (t < NBK2) ? bhist2[t] : 0;
    s[t] = b0;
    __syncthreads();
    for (int off = 1; off < 256; off <<= 1) {
        int u = (t >= off) ? s[t - off] : 0;
        __syncthreads();
        s[t] += u;
        __syncthreads();
    }
    int ex2 = (t > 0) ? s[t - 1] : 0;
    if (t < NBK2) { bbase2[t] = ex2; bcur2[t] = ex2; }
}

// bin edges into bucket-contiguous record array (src,tgt), LDS-staged
__global__ __launch_bounds__(256) void bin_kernel(
    const int* __restrict__ ei1, const int* __restrict__ ei2,
    int* __restrict__ bcur1, int* __restrict__ bcur2,
    uint2* __restrict__ gbuf1, uint2* __restrict__ gbuf2)
{
    __shared__ unsigned int lcnt[512];
    __shared__ unsigned int lofs[512];
    __shared__ unsigned int lpos[512];
    __shared__ unsigned int gbase[512];
    __shared__ unsigned int swarp[256];
    __shared__ uint2 lbuf[CH];

    const int* ei; int* bcur; uint2* gbuf; int nE, nbk, chunk;
    if (blockIdx.x < NCH1) {
        ei = ei1; bcur = bcur1; gbuf = gbuf1; nE = NE1; nbk = NBK1; chunk = blockIdx.x;
    } else {
        ei = ei2; bcur = bcur2; gbuf = gbuf2; nE = NE2; nbk = NBK2; chunk = blockIdx.x - NCH1;
    }
    int base = chunk * CH;
    int nb = nE - base; if (nb > CH) nb = CH;
    int t = threadIdx.x;

    for (int i = t; i < 512; i += 256) { lcnt[i] = 0; lpos[i] = 0; }
    __syncthreads();

    int srcv[16], tgtv[16];
    #pragma unroll
    for (int i = 0; i < 16; ++i) {
        int e = base + i * 256 + t;
        if (e < nE) {
            tgtv[i] = ei[nE + e];
            srcv[i] = ei[e];
            atomicAdd(&lcnt[tgtv[i] >> 8], 1u);
        } else tgtv[i] = -1;
    }
    __syncthreads();

    unsigned a0 = lcnt[2 * t], a1 = lcnt[2 * t + 1];
    swarp[t] = a0 + a1;
    __syncthreads();
    for (int off = 1; off < 256; off <<= 1) {
        unsigned v = (t >= off) ? swarp[t - off] : 0;
        __syncthreads();
        swarp[t] += v;
        __syncthreads();
    }
    unsigned ex = (t > 0) ? swarp[t - 1] : 0;
    lofs[2 * t] = ex;
    lofs[2 * t + 1] = ex + a0;
    if (2 * t < nbk && a0) gbase[2 * t] = atomicAdd(&bcur[2 * t], (int)a0);
    if (2 * t + 1 < nbk && a1) gbase[2 * t + 1] = atomicAdd(&bcur[2 * t + 1], (int)a1);
    __syncthreads();

    #pragma unroll
    for (int i = 0; i < 16; ++i) {
        if (tgtv[i] >= 0) {
            int b = tgtv[i] >> 8;
            unsigned idx = lofs[b] + atomicAdd(&lpos[b], 1u);
            lbuf[idx] = make_uint2((unsigned)srcv[i], (unsigned)tgtv[i]);
        }
    }
    __syncthreads();

    for (int i = t; i < nb; i += 256) {
        uint2 r = lbuf[i];
        int b = (int)(r.y >> 8);
        unsigned gi = gbase[b] + ((unsigned)i - lofs[b]);
        gbuf[gi] = r;
    }
}

// one workgroup per bucket: node-local hist + scan in LDS, rs and csr writes coalesced
__global__ __launch_bounds__(256) void bucket_csr_kernel(
    const uint2* __restrict__ gbuf1, const uint2* __restrict__ gbuf2,
    const int* __restrict__ bbase1, const int* __restrict__ bbase2,
    int* __restrict__ rs1, int* __restrict__ rs2,
    int* __restrict__ csr1, int* __restrict__ csr2)
{
    __shared__ unsigned int lhist[256];
    __shared__ unsigned int lcur[256];
    __shared__ unsigned int sscan[256];
    __shared__ unsigned int lbuf[MAXBUF];
    const uint2* gbuf; const int* bbase; int* rs; int* csr; int bucket, ntot;
    if (blockIdx.x < NBK1) {
        gbuf = gbuf1; bbase = bbase1; rs = rs1; csr = csr1; bucket = blockIdx.x; ntot = NMID;
    } else {
        gbuf = gbuf2; bbase = bbase2; rs = rs2; csr = csr2; bucket = blockIdx.x - NBK1; ntot = NTGT;
    }
    int base = bbase[bucket];
    int size = bbase[bucket + 1] - base;
    int node0 = bucket << 8;
    int nnode = ntot - node0; if (nnode > 256) nnode = 256;
    int t = threadIdx.x;
    lhist[t] = 0;
    __syncthreads();
    for (int i = t; i < size; i += 256)
        atomicAdd(&lhist[gbuf[base + i].y & 255], 1u);
    __syncthreads();
    unsigned v = lhist[t];
    sscan[t] = v;
    __syncthreads();
    for (int off = 1; off < 256; off <<= 1) {
        unsigned u = (t >= off) ? sscan[t - off] : 0;
        __syncthreads();
        sscan[t] += u;
        __syncthreads();
    }
    unsigned ex = (t > 0) ? sscan[t - 1] : 0;
    lcur[t] = ex;
    if (t < nnode) rs[node0 + t] = base + (int)ex;
    __syncthreads();
    for (int i = t; i < size; i += 256) {
        uint2 r = gbuf[base + i];
        unsigned pos = atomicAdd(&lcur[r.y & 255], 1u);
        lbuf[pos] = r.x;
    }
    __syncthreads();
    for (int i = t; i < size; i += 256)
        csr[base + i] = (int)lbuf[i];
}

// ---------------- gathers ----------------

__global__ __launch_bounds__(256) void gather1_kernel(
    const unsigned short* __restrict__ xb, const int* __restrict__ rs,
    const int* __restrict__ csr, unsigned short* __restrict__ aggnb)
{
    int node = blockIdx.x * 4 + (threadIdx.x >> 6);
    if (node >= NMID) return;
    int lane = threadIdx.x & 63;
    int s = rs[node];
    int d = rs[node + 1] - s;
    const char* xbase = (const char*)xb;
    unsigned int voff = (unsigned int)lane * 4u;
    float a0 = 0.f, a1 = 0.f, b0 = 0.f, b1 = 0.f;
    float c0 = 0.f, c1 = 0.f, e0 = 0.f, e1 = 0.f;
    for (int base = 0; base < d; base += 64) {
        int nb = d - base; if (nb > 64) nb = 64;
        int li = base + lane; if (li > d - 1) li = d - 1;
        int my = csr[s + li];
        int j = 0;
        for (; j + 3 < nb; j += 4) {
            int s0 = __builtin_amdgcn_readlane(my, j);
            int s1 = __builtin_amdgcn_readlane(my, j + 1);
            int s2 = __builtin_amdgcn_readlane(my, j + 2);
            int s3 = __builtin_amdgcn_readlane(my, j + 3);
            unsigned int u0 = *(const unsigned int*)(xbase + (((size_t)(unsigned)s0) << 8) + voff);
            unsigned int u1 = *(const unsigned int*)(xbase + (((size_t)(unsigned)s1) << 8) + voff);
            unsigned int u2 = *(const unsigned int*)(xbase + (((size_t)(unsigned)s2) << 8) + voff);
            unsigned int u3 = *(const unsigned int*)(xbase + (((size_t)(unsigned)s3) << 8) + voff);
            a0 += bf_lo(u0); a1 += bf_hi(u0);
            b0 += bf_lo(u1); b1 += bf_hi(u1);
            c0 += bf_lo(u2); c1 += bf_hi(u2);
            e0 += bf_lo(u3); e1 += bf_hi(u3);
        }
        for (; j < nb; ++j) {
            int s0 = __builtin_amdgcn_readlane(my, j);
            unsigned int u0 = *(const unsigned int*)(xbase + (((size_t)(unsigned)s0) << 8) + voff);
            a0 += bf_lo(u0); a1 += bf_hi(u0);
        }
    }
    float inv = (d > 0) ? 1.0f / (float)d : 0.f;
    float r0 = (a0 + b0 + c0 + e0) * inv;
    float r1 = (a1 + b1 + c1 + e1) * inv;
    unsigned int packed = (unsigned int)f2bf(r0) | ((unsigned int)f2bf(r1) << 16);
    *(unsigned int*)(aggnb + (long long)node * DIN + lane * 2) = packed;
}

__global__ __launch_bounds__(256) void gather2_kernel(
    const float* __restrict__ p, const int* __restrict__ rs,
    const int* __restrict__ csr, float* __restrict__ aggp)
{
    int node = blockIdx.x * 4 + (threadIdx.x >> 6);
    if (node >= NTGT) return;
    int lane = threadIdx.x & 63;
    int s = rs[node];
    int d = rs[node + 1] - s;
    const char* pbase = (const char*)p;
    unsigned int voff = (unsigned int)lane * 4u;
    float a = 0.f, b = 0.f, c = 0.f, e = 0.f;
    for (int base = 0; base < d; base += 64) {
        int nb = d - base; if (nb > 64) nb = 64;
        int li = base + lane; if (li > d - 1) li = d - 1;
        int my = csr[s + li];
        int j = 0;
        for (; j + 3 < nb; j += 4) {
            int s0 = __builtin_amdgcn_readlane(my, j);
            int s1 = __builtin_amdgcn_readlane(my, j + 1);
            int s2 = __builtin_amdgcn_readlane(my, j + 2);
            int s3 = __builtin_amdgcn_readlane(my, j + 3);
            a += *(const float*)(pbase + (((size_t)(unsigned)s0) << 8) + voff);
            b += *(const float*)(pbase + (((size_t)(unsigned)s1) << 8) + voff);
            c += *(const float*)(pbase + (((size_t)(unsigned)s2) << 8) + voff);
            e += *(const float*)(pbase + (((size_t)(unsigned)s3) << 8) + voff);
        }
        for (; j < nb; ++j) {
            int s0 = __builtin_amdgcn_readlane(my, j);
            a += *(const float*)(pbase + (((size_t)(unsigned)s0) << 8) + voff);
        }
    }
    float inv = (d > 0) ? 1.0f / (float)d : 0.f;
    aggp[(long long)node * DOUT + lane] = (a + b + c + e) * inv;
}

// ---------------- MFMA GEMMs ----------------
#define LDSP 40

__global__ __launch_bounds__(256) void gemm1_mfma(
    const unsigned short* __restrict__ aggnb, const unsigned short* __restrict__ xb,
    const unsigned short* __restrict__ WT, const float* __restrict__ bias,
    unsigned short* __restrict__ h)
{
    __shared__ unsigned short Asm[128 * LDSP];
    __shared__ unsigned short Bsm[128 * LDSP];
    const int tid = threadIdx.x;
    const int bm = blockIdx.x * 128;
    const int bn = blockIdx.y * 128;
    const int wave = tid >> 6, lane = tid & 63;
    const int wr = wave >> 1, wc = wave & 1;
    const int lrow = lane & 15, quad = lane >> 4;

    f32x4 acc[4][4];
    #pragma unroll
    for (int i = 0; i < 4; ++i)
        #pragma unroll
        for (int j = 0; j < 4; ++j)
            acc[i][j] = (f32x4){0.f, 0.f, 0.f, 0.f};

    for (int k0 = 0; k0 < 256; k0 += 32) {
        #pragma unroll
        for (int c = tid; c < 512; c += 256) {
            int row = c >> 2, seg = c & 3;
            int grow = bm + row; if (grow >= NMID) grow = NMID - 1;
            int gk = k0 + seg * 8;
            const unsigned short* src = (gk < DIN)
                ? (aggnb + (long long)grow * DIN + gk)
                : (xb + (long long)grow * DIN + (gk - DIN));
            *(uint4*)(Asm + row * LDSP + seg * 8) = *(const uint4*)src;
        }
        #pragma unroll
        for (int c = tid; c < 512; c += 256) {
            int row = c >> 2, seg = c & 3;
            *(uint4*)(Bsm + row * LDSP + seg * 8) =
                *(const uint4*)(WT + (long long)(bn + row) * 256 + k0 + seg * 8);
        }
        __syncthreads();
        bf16x8 af[4], bfr[4];
        #pragma unroll
        for (int mi = 0; mi < 4; ++mi)
            af[mi] = *(const bf16x8*)(Asm + (wr * 64 + mi * 16 + lrow) * LDSP + quad * 8);
        #pragma unroll
        for (int ni = 0; ni < 4; ++ni)
            bfr[ni] = *(const bf16x8*)(Bsm + (wc * 64 + ni * 16 + lrow) * LDSP + quad * 8);
        #pragma unroll
        for (int mi = 0; mi < 4; ++mi)
            #pragma unroll
            for (int ni = 0; ni < 4; ++ni)
                acc[mi][ni] = __builtin_amdgcn_mfma_f32_16x16x32_bf16(
                    af[mi], bfr[ni], acc[mi][ni], 0, 0, 0);
        __syncthreads();
    }
    #pragma unroll
    for (int mi = 0; mi < 4; ++mi) {
        #pragma unroll
        for (int ni = 0; ni < 4; ++ni) {
            int col = bn + wc * 64 + ni * 16 + lrow;
            float bv = bias[col];
            #pragma unroll
            for (int r = 0; r < 4; ++r) {
                int row = bm + wr * 64 + mi * 16 + quad * 4 + r;
                if (row < NMID) {
                    float v = acc[mi][ni][r] + bv;
                    h[(long long)row * DHID + col] = f2bf(fmaxf(v, 0.0f));
                }
            }
        }
    }
}

template <bool FIN>
__global__ __launch_bounds__(256) void gemm_n64_mfma(
    const unsigned short* __restrict__ h, const unsigned short* __restrict__ WT,
    int nofs, int M,
    const float* __restrict__ bias, const float* __restrict__ aggp,
    float* __restrict__ outp)
{
    __shared__ unsigned short Asm[128 * LDSP];
    __shared__ unsigned short Bsm[64 * LDSP];
    const int tid = threadIdx.x;
    const int bm = blockIdx.x * 128;
    const int wave = tid >> 6, lane = tid & 63;
    const int lrow = lane & 15, quad = lane >> 4;

    f32x4 acc[2][4];
    #pragma unroll
    for (int i = 0; i < 2; ++i)
        #pragma unroll
        for (int j = 0; j < 4; ++j)
            acc[i][j] = (f32x4){0.f, 0.f, 0.f, 0.f};

    for (int k0 = 0; k0 < 256; k0 += 32) {
        #pragma unroll
        for (int c = tid; c < 512; c += 256) {
            int row = c >> 2, seg = c & 3;
            int grow = bm + row; if (grow >= M) grow = M - 1;
            *(uint4*)(Asm + row * LDSP + seg * 8) =
                *(const uint4*)(h + (long long)grow * DHID + k0 + seg * 8);
        }
        {
            int row = tid >> 2, seg = tid & 3;
            *(uint4*)(Bsm + row * LDSP + seg * 8) =
                *(const uint4*)(WT + (long long)(nofs + row) * 256 + k0 + seg * 8);
        }
        __syncthreads();
        bf16x8 af[2], bfr[4];
        #pragma unroll
        for (int mi = 0; mi < 2; ++mi)
            af[mi] = *(const bf16x8*)(Asm + (wave * 32 + mi * 16 + lrow) * LDSP + quad * 8);
        #pragma unroll
        for (int ni = 0; ni < 4; ++ni)
            bfr[ni] = *(const bf16x8*)(Bsm + (ni * 16 + lrow) * LDSP + quad * 8);
        #pragma unroll
        for (int mi = 0; mi < 2; ++mi)
            #pragma unroll
            for (int ni = 0; ni < 4; ++ni)
                acc[mi][ni] = __builtin_amdgcn_mfma_f32_16x16x32_bf16(
                    af[mi], bfr[ni], acc[mi][ni], 0, 0, 0);
        __syncthreads();
    }
    #pragma unroll
    for (int mi = 0; mi < 2; ++mi) {
        #pragma unroll
        for (int ni = 0; ni < 4; ++ni) {
            int col = ni * 16 + lrow;
            float bv = FIN ? bias[col] : 0.f;
            #pragma unroll
            for (int r = 0; r < 4; ++r) {
                int row = bm + wave * 32 + mi * 16 + quad * 4 + r;
                if (row < M) {
                    float v = acc[mi][ni][r] + bv;
                    if (FIN) v += aggp[(long long)row * DOUT + col];
                    outp[(long long)row * DOUT + col] = v;
                }
            }
        }
    }
}

extern "C" void kernel_launch(void* const* d_in, const int* in_sizes, int n_in,
                              void* d_out, int out_size, void* d_ws, size_t ws_size,
                              hipStream_t stream) {
    const float* x   = (const float*)d_in[0];
    const int*   ei1 = (const int*)d_in[1];
    const int*   ei2 = (const int*)d_in[2];
    const float* Wl1 = (const float*)d_in[3];
    const float* Wr1 = (const float*)d_in[4];
    const float* b1  = (const float*)d_in[5];
    const float* Wl2 = (const float*)d_in[6];
    const float* Wr2 = (const float*)d_in[7];
    const float* b2  = (const float*)d_in[8];
    float* out = (float*)d_out;

    unsigned short* xb    = (unsigned short*)d_ws;
    unsigned short* aggnb = xb + (size_t)NSRC * DIN;
    unsigned short* h     = aggnb + (size_t)NMID * DIN;
    unsigned short* WT1   = h + (size_t)NMID * DHID;
    unsigned short* WT2   = WT1 + 256 * 256;
    float* p    = (float*)(WT2 + 128 * 256);
    float* aggp = p + (size_t)NMID * DOUT;
    int* rs1    = (int*)(aggp + (size_t)NTGT * DOUT);
    int* rs2    = rs1 + (NMID + 1);
    int* bhist1 = rs2 + (NTGT + 1);
    int* bhist2 = bhist1 + NBK1;
    int* bbase1 = bhist2 + NBK2;
    int* bbase2 = bbase1 + (NBK1 + 1);
    int* bcur1  = bbase2 + (NBK2 + 1);
    int* bcur2  = bcur1 + NBK1;
    int* csr1   = bcur2 + NBK2 + 1;
    int* csr2   = csr1 + NE1;
    uint2* gbuf1 = (uint2*)(((size_t)(csr2 + NE2) + 15) & ~(size_t)15);
    uint2* gbuf2 = gbuf1 + NE1;

    convert_all_kernel<<<(XCH + 65536 + 32768 + 255) / 256, 256, 0, stream>>>(
        x, Wl1, Wr1, Wl2, Wr2, xb, WT1, WT2);

    hipMemsetAsync(bhist1, 0, (size_t)(NBK1 + NBK2) * 4, stream);
    bucket_hist_kernel<<<NHC1 + NHC2, 256, 0, stream>>>(ei1, ei2, bhist1, bhist2);
    bucket_scan_kernel<<<1, 256, 0, stream>>>(bhist1, bhist2, bbase1, bbase2,
                                              bcur1, bcur2, rs1, rs2);
    bin_kernel<<<NCH1 + NCH2, 256, 0, stream>>>(ei1, ei2, bcur1, bcur2, gbuf1, gbuf2);
    bucket_csr_kernel<<<NBK1 + NBK2, 256, 0, stream>>>(
        gbuf1, gbuf2, bbase1, bbase2, rs1, rs2, csr1, csr2);

    gather1_kernel<<<(NMID + 3) / 4, 256, 0, stream>>>(xb, rs1, csr1, aggnb);
    {
        dim3 grid((NMID + 127) / 128, 2);
        gemm1_mfma<<<grid, 256, 0, stream>>>(aggnb, xb, WT1, b1, h);
    }
    gemm_n64_mfma<false><<<(NMID + 127) / 128, 256, 0, stream>>>(
        h, WT2, 0, NMID, nullptr, nullptr, p);
    gather2_kernel<<<(NTGT + 3) / 4, 256, 0, stream>>>(p, rs2, csr2, aggp);
    gemm_n64_mfma<true><<<(NTGT + 127) / 128, 256, 0, stream>>>(
        h, WT2, 64, NTGT, b2, aggp, out);
}

// Round 7
// 406.409 us; speedup vs baseline: 9.4746x; 1.0669x over previous
//
#include <hip/hip_runtime.h>

// GraphSAGE 2-layer. Round 7: register-prefetch pipelined gemm1; gemm2_dual
// computes p=h@Wl2 and q=h[:50K]@Wr2+b2 in one pass; gather2_final writes out
// directly (final kernel and aggp eliminated). CSR build from round 6.

#define NSRC 200000
#define NMID 100000
#define NTGT 50000
#define NE1  1600000
#define NE2  800000
#define DIN  128
#define DHID 256
#define DOUT 64

#define XCH (NSRC * 16)

#define CH   4096
#define NBK1 391
#define NBK2 196
#define NCH1 ((NE1 + CH - 1) / CH)
#define NCH2 ((NE2 + CH - 1) / CH)
#define HCH  8192
#define NHC1 ((NE1 + HCH - 1) / HCH)
#define NHC2 ((NE2 + HCH - 1) / HCH)
#define MAXBUF 6144

typedef __attribute__((ext_vector_type(8))) short bf16x8;
typedef __attribute__((ext_vector_type(4))) float f32x4;

__device__ __forceinline__ unsigned short f2bf(float f) {
    unsigned int u = __builtin_bit_cast(unsigned int, f);
    u += 0x7FFFu + ((u >> 16) & 1u);
    return (unsigned short)(u >> 16);
}
__device__ __forceinline__ float bf_lo(unsigned int u) {
    return __builtin_bit_cast(float, u << 16);
}
__device__ __forceinline__ float bf_hi(unsigned int u) {
    return __builtin_bit_cast(float, u & 0xFFFF0000u);
}

// ---------------- fused converts ----------------
__global__ __launch_bounds__(256) void convert_all_kernel(
    const float* __restrict__ x,
    const float* __restrict__ Wl1, const float* __restrict__ Wr1,
    const float* __restrict__ Wl2, const float* __restrict__ Wr2,
    unsigned short* __restrict__ xb, unsigned short* __restrict__ WT1,
    unsigned short* __restrict__ WT2)
{
    int gid = blockIdx.x * 256 + threadIdx.x;
    if (gid < XCH) {
        const float4 v0 = *(const float4*)(x + (long long)gid * 8);
        const float4 v1 = *(const float4*)(x + (long long)gid * 8 + 4);
        unsigned short o[8] = {f2bf(v0.x), f2bf(v0.y), f2bf(v0.z), f2bf(v0.w),
                               f2bf(v1.x), f2bf(v1.y), f2bf(v1.z), f2bf(v1.w)};
        *(uint4*)(xb + (long long)gid * 8) = *(const uint4*)o;
        return;
    }
    int g = gid - XCH;
    if (g < 65536) {
        int n = g >> 8, k = g & 255;
        float v = (k < DIN) ? Wl1[(long long)k * DHID + n]
                            : Wr1[(long long)(k - DIN) * DHID + n];
        WT1[g] = f2bf(v);
        return;
    }
    g -= 65536;
    if (g < 32768) {
        int n2 = g >> 8, k = g & 255;
        float v = (n2 < DOUT) ? Wl2[(long long)k * DOUT + n2]
                              : Wr2[(long long)k * DOUT + (n2 - DOUT)];
        WT2[g] = f2bf(v);
    }
}

// ---------------- bucket-first CSR build ----------------

__global__ __launch_bounds__(256) void bucket_hist_kernel(
    const int* __restrict__ ei1, const int* __restrict__ ei2,
    int* __restrict__ bhist1, int* __restrict__ bhist2)
{
    __shared__ unsigned int lh[512];
    const int* ei; int* bh; int nE, nbk, chunk;
    if (blockIdx.x < NHC1) { ei = ei1; bh = bhist1; nE = NE1; nbk = NBK1; chunk = blockIdx.x; }
    else { ei = ei2; bh = bhist2; nE = NE2; nbk = NBK2; chunk = blockIdx.x - NHC1; }
    int t = threadIdx.x;
    lh[t] = 0; lh[t + 256] = 0;
    __syncthreads();
    int base = chunk * HCH;
    int end = nE < base + HCH ? nE : base + HCH;
    for (int e = base + t; e < end; e += 256)
        atomicAdd(&lh[((unsigned)ei[nE + e]) >> 8], 1u);
    __syncthreads();
    if (t < nbk && lh[t]) atomicAdd(&bh[t], (int)lh[t]);
    if (t + 256 < nbk && lh[t + 256]) atomicAdd(&bh[t + 256], (int)lh[t + 256]);
}

__global__ __launch_bounds__(256) void bucket_scan_kernel(
    const int* __restrict__ bhist1, const int* __restrict__ bhist2,
    int* __restrict__ bbase1, int* __restrict__ bbase2,
    int* __restrict__ bcur1, int* __restrict__ bcur2,
    int* __restrict__ rs1, int* __restrict__ rs2)
{
    __shared__ int s[256];
    int t = threadIdx.x;
    int a0 = (2 * t < NBK1) ? bhist1[2 * t] : 0;
    int a1 = (2 * t + 1 < NBK1) ? bhist1[2 * t + 1] : 0;
    s[t] = a0 + a1;
    __syncthreads();
    for (int off = 1; off < 256; off <<= 1) {
        int u = (t >= off) ? s[t - off] : 0;
        __syncthreads();
        s[t] += u;
        __syncthreads();
    }
    int ex = (t > 0) ? s[t - 1] : 0;
    if (2 * t < NBK1)     { bbase1[2 * t] = ex;      bcur1[2 * t] = ex; }
    if (2 * t + 1 < NBK1) { bbase1[2 * t + 1] = ex + a0; bcur1[2 * t + 1] = ex + a0; }
    if (t == 0) { bbase1[NBK1] = NE1; rs1[NMID] = NE1; bbase2[NBK2] = NE2; rs2[NTGT] = NE2; }
    __syncthreads();
    int b0 = (t < NBK2) ? bhist2[t] : 0;
    s[t] = b0;
    __syncthreads();
    for (int off = 1; off < 256; off <<= 1) {
        int u = (t >= off) ? s[t - off] : 0;
        __syncthreads();
        s[t] += u;
        __syncthreads();
    }
    int ex2 = (t > 0) ? s[t - 1] : 0;
    if (t < NBK2) { bbase2[t] = ex2; bcur2[t] = ex2; }
}

__global__ __launch_bounds__(256) void bin_kernel(
    const int* __restrict__ ei1, const int* __restrict__ ei2,
    int* __restrict__ bcur1, int* __restrict__ bcur2,
    uint2* __restrict__ gbuf1, uint2* __restrict__ gbuf2)
{
    __shared__ unsigned int lcnt[512];
    __shared__ unsigned int lofs[512];
    __shared__ unsigned int lpos[512];
    __shared__ unsigned int gbase[512];
    __shared__ unsigned int swarp[256];
    __shared__ uint2 lbuf[CH];

    const int* ei; int* bcur; uint2* gbuf; int nE, nbk, chunk;
    if (blockIdx.x < NCH1) {
        ei = ei1; bcur = bcur1; gbuf = gbuf1; nE = NE1; nbk = NBK1; chunk = blockIdx.x;
    } else {
        ei = ei2; bcur = bcur2; gbuf = gbuf2; nE = NE2; nbk = NBK2; chunk = blockIdx.x - NCH1;
    }
    int base = chunk * CH;
    int nb = nE - base; if (nb > CH) nb = CH;
    int t = threadIdx.x;

    for (int i = t; i < 512; i += 256) { lcnt[i] = 0; lpos[i] = 0; }
    __syncthreads();

    int srcv[16], tgtv[16];
    #pragma unroll
    for (int i = 0; i < 16; ++i) {
        int e = base + i * 256 + t;
        if (e < nE) {
            tgtv[i] = ei[nE + e];
            srcv[i] = ei[e];
            atomicAdd(&lcnt[tgtv[i] >> 8], 1u);
        } else tgtv[i] = -1;
    }
    __syncthreads();

    unsigned a0 = lcnt[2 * t], a1 = lcnt[2 * t + 1];
    swarp[t] = a0 + a1;
    __syncthreads();
    for (int off = 1; off < 256; off <<= 1) {
        unsigned v = (t >= off) ? swarp[t - off] : 0;
        __syncthreads();
        swarp[t] += v;
        __syncthreads();
    }
    unsigned ex = (t > 0) ? swarp[t - 1] : 0;
    lofs[2 * t] = ex;
    lofs[2 * t + 1] = ex + a0;
    if (2 * t < nbk && a0) gbase[2 * t] = atomicAdd(&bcur[2 * t], (int)a0);
    if (2 * t + 1 < nbk && a1) gbase[2 * t + 1] = atomicAdd(&bcur[2 * t + 1], (int)a1);
    __syncthreads();

    #pragma unroll
    for (int i = 0; i < 16; ++i) {
        if (tgtv[i] >= 0) {
            int b = tgtv[i] >> 8;
            unsigned idx = lofs[b] + atomicAdd(&lpos[b], 1u);
            lbuf[idx] = make_uint2((unsigned)srcv[i], (unsigned)tgtv[i]);
        }
    }
    __syncthreads();

    for (int i = t; i < nb; i += 256) {
        uint2 r = lbuf[i];
        int b = (int)(r.y >> 8);
        unsigned gi = gbase[b] + ((unsigned)i - lofs[b]);
        gbuf[gi] = r;
    }
}

__global__ __launch_bounds__(256) void bucket_csr_kernel(
    const uint2* __restrict__ gbuf1, const uint2* __restrict__ gbuf2,
    const int* __restrict__ bbase1, const int* __restrict__ bbase2,
    int* __restrict__ rs1, int* __restrict__ rs2,
    int* __restrict__ csr1, int* __restrict__ csr2)
{
    __shared__ unsigned int lhist[256];
    __shared__ unsigned int lcur[256];
    __shared__ unsigned int sscan[256];
    __shared__ unsigned int lbuf[MAXBUF];
    const uint2* gbuf; const int* bbase; int* rs; int* csr; int bucket, ntot;
    if (blockIdx.x < NBK1) {
        gbuf = gbuf1; bbase = bbase1; rs = rs1; csr = csr1; bucket = blockIdx.x; ntot = NMID;
    } else {
        gbuf = gbuf2; bbase = bbase2; rs = rs2; csr = csr2; bucket = blockIdx.x - NBK1; ntot = NTGT;
    }
    int base = bbase[bucket];
    int size = bbase[bucket + 1] - base;
    int node0 = bucket << 8;
    int nnode = ntot - node0; if (nnode > 256) nnode = 256;
    int t = threadIdx.x;
    lhist[t] = 0;
    __syncthreads();
    for (int i = t; i < size; i += 256)
        atomicAdd(&lhist[gbuf[base + i].y & 255], 1u);
    __syncthreads();
    unsigned v = lhist[t];
    sscan[t] = v;
    __syncthreads();
    for (int off = 1; off < 256; off <<= 1) {
        unsigned u = (t >= off) ? sscan[t - off] : 0;
        __syncthreads();
        sscan[t] += u;
        __syncthreads();
    }
    unsigned ex = (t > 0) ? sscan[t - 1] : 0;
    lcur[t] = ex;
    if (t < nnode) rs[node0 + t] = base + (int)ex;
    __syncthreads();
    for (int i = t; i < size; i += 256) {
        uint2 r = gbuf[base + i];
        unsigned pos = atomicAdd(&lcur[r.y & 255], 1u);
        lbuf[pos] = r.x;
    }
    __syncthreads();
    for (int i = t; i < size; i += 256)
        csr[base + i] = (int)lbuf[i];
}

// ---------------- gathers ----------------

__global__ __launch_bounds__(256) void gather1_kernel(
    const unsigned short* __restrict__ xb, const int* __restrict__ rs,
    const int* __restrict__ csr, unsigned short* __restrict__ aggnb)
{
    int node = blockIdx.x * 4 + (threadIdx.x >> 6);
    if (node >= NMID) return;
    int lane = threadIdx.x & 63;
    int s = rs[node];
    int d = rs[node + 1] - s;
    const char* xbase = (const char*)xb;
    unsigned int voff = (unsigned int)lane * 4u;
    float a0 = 0.f, a1 = 0.f, b0 = 0.f, b1 = 0.f;
    float c0 = 0.f, c1 = 0.f, e0 = 0.f, e1 = 0.f;
    for (int base = 0; base < d; base += 64) {
        int nb = d - base; if (nb > 64) nb = 64;
        int li = base + lane; if (li > d - 1) li = d - 1;
        int my = csr[s + li];
        int j = 0;
        for (; j + 3 < nb; j += 4) {
            int s0 = __builtin_amdgcn_readlane(my, j);
            int s1 = __builtin_amdgcn_readlane(my, j + 1);
            int s2 = __builtin_amdgcn_readlane(my, j + 2);
            int s3 = __builtin_amdgcn_readlane(my, j + 3);
            unsigned int u0 = *(const unsigned int*)(xbase + (((size_t)(unsigned)s0) << 8) + voff);
            unsigned int u1 = *(const unsigned int*)(xbase + (((size_t)(unsigned)s1) << 8) + voff);
            unsigned int u2 = *(const unsigned int*)(xbase + (((size_t)(unsigned)s2) << 8) + voff);
            unsigned int u3 = *(const unsigned int*)(xbase + (((size_t)(unsigned)s3) << 8) + voff);
            a0 += bf_lo(u0); a1 += bf_hi(u0);
            b0 += bf_lo(u1); b1 += bf_hi(u1);
            c0 += bf_lo(u2); c1 += bf_hi(u2);
            e0 += bf_lo(u3); e1 += bf_hi(u3);
        }
        for (; j < nb; ++j) {
            int s0 = __builtin_amdgcn_readlane(my, j);
            unsigned int u0 = *(const unsigned int*)(xbase + (((size_t)(unsigned)s0) << 8) + voff);
            a0 += bf_lo(u0); a1 += bf_hi(u0);
        }
    }
    float inv = (d > 0) ? 1.0f / (float)d : 0.f;
    float r0 = (a0 + b0 + c0 + e0) * inv;
    float r1 = (a1 + b1 + c1 + e1) * inv;
    unsigned int packed = (unsigned int)f2bf(r0) | ((unsigned int)f2bf(r1) << 16);
    *(unsigned int*)(aggnb + (long long)node * DIN + lane * 2) = packed;
}

// out[node] = q[node] + mean_{src in N(node)} p[src]
__global__ __launch_bounds__(256) void gather2_final_kernel(
    const float* __restrict__ p, const float* __restrict__ qb,
    const int* __restrict__ rs, const int* __restrict__ csr,
    float* __restrict__ out)
{
    int node = blockIdx.x * 4 + (threadIdx.x >> 6);
    if (node >= NTGT) return;
    int lane = threadIdx.x & 63;
    int s = rs[node];
    int d = rs[node + 1] - s;
    const char* pbase = (const char*)p;
    unsigned int voff = (unsigned int)lane * 4u;
    float a = 0.f, b = 0.f, c = 0.f, e = 0.f;
    for (int base = 0; base < d; base += 64) {
        int nb = d - base; if (nb > 64) nb = 64;
        int li = base + lane; if (li > d - 1) li = d - 1;
        int my = csr[s + li];
        int j = 0;
        for (; j + 3 < nb; j += 4) {
            int s0 = __builtin_amdgcn_readlane(my, j);
            int s1 = __builtin_amdgcn_readlane(my, j + 1);
            int s2 = __builtin_amdgcn_readlane(my, j + 2);
            int s3 = __builtin_amdgcn_readlane(my, j + 3);
            a += *(const float*)(pbase + (((size_t)(unsigned)s0) << 8) + voff);
            b += *(const float*)(pbase + (((size_t)(unsigned)s1) << 8) + voff);
            c += *(const float*)(pbase + (((size_t)(unsigned)s2) << 8) + voff);
            e += *(const float*)(pbase + (((size_t)(unsigned)s3) << 8) + voff);
        }
        for (; j < nb; ++j) {
            int s0 = __builtin_amdgcn_readlane(my, j);
            a += *(const float*)(pbase + (((size_t)(unsigned)s0) << 8) + voff);
        }
    }
    float inv = (d > 0) ? 1.0f / (float)d : 0.f;
    out[(long long)node * DOUT + lane] =
        qb[(long long)node * DOUT + lane] + (a + b + c + e) * inv;
}

// ---------------- MFMA GEMMs ----------------
#define LDSP 40

// h = relu([aggnb|xb] @ WT1^T + b1), register-prefetch pipelined
__global__ __launch_bounds__(256) void gemm1_mfma(
    const unsigned short* __restrict__ aggnb, const unsigned short* __restrict__ xb,
    const unsigned short* __restrict__ WT, const float* __restrict__ bias,
    unsigned short* __restrict__ h)
{
    __shared__ unsigned short Asm[128 * LDSP];
    __shared__ unsigned short Bsm[128 * LDSP];
    const int tid = threadIdx.x;
    const int bm = blockIdx.x * 128;
    const int bn = blockIdx.y * 128;
    const int wave = tid >> 6, lane = tid & 63;
    const int wr = wave >> 1, wc = wave & 1;
    const int lrow = lane & 15, quad = lane >> 4;

    // per-thread staging coords (2 chunks each for A and B)
    const int c0r = tid >> 2, c0s = tid & 3;          // chunk tid
    const int c1r = (tid + 256) >> 2, c1s = tid & 3;  // chunk tid+256
    int growA0 = bm + c0r; if (growA0 >= NMID) growA0 = NMID - 1;
    int growA1 = bm + c1r; if (growA1 >= NMID) growA1 = NMID - 1;

    uint4 pa0, pa1, pb0, pb1;
    auto gload = [&](int k0) {
        int gk0 = k0 + c0s * 8;
        const unsigned short* sA0 = (gk0 < DIN)
            ? (aggnb + (long long)growA0 * DIN + gk0)
            : (xb + (long long)growA0 * DIN + (gk0 - DIN));
        pa0 = *(const uint4*)sA0;
        const unsigned short* sA1 = (gk0 < DIN)
            ? (aggnb + (long long)growA1 * DIN + gk0)
            : (xb + (long long)growA1 * DIN + (gk0 - DIN));
        pa1 = *(const uint4*)sA1;
        pb0 = *(const uint4*)(WT + (long long)(bn + c0r) * 256 + k0 + c0s * 8);
        pb1 = *(const uint4*)(WT + (long long)(bn + c1r) * 256 + k0 + c1s * 8);
    };

    f32x4 acc[4][4];
    #pragma unroll
    for (int i = 0; i < 4; ++i)
        #pragma unroll
        for (int j = 0; j < 4; ++j)
            acc[i][j] = (f32x4){0.f, 0.f, 0.f, 0.f};

    gload(0);
    for (int it = 0; it < 8; ++it) {
        if (it) __syncthreads();
        *(uint4*)(Asm + c0r * LDSP + c0s * 8) = pa0;
        *(uint4*)(Asm + c1r * LDSP + c1s * 8) = pa1;
        *(uint4*)(Bsm + c0r * LDSP + c0s * 8) = pb0;
        *(uint4*)(Bsm + c1r * LDSP + c1s * 8) = pb1;
        __syncthreads();
        if (it < 7) gload((it + 1) * 32);
        bf16x8 af[4], bfr[4];
        #pragma unroll
        for (int mi = 0; mi < 4; ++mi)
            af[mi] = *(const bf16x8*)(Asm + (wr * 64 + mi * 16 + lrow) * LDSP + quad * 8);
        #pragma unroll
        for (int ni = 0; ni < 4; ++ni)
            bfr[ni] = *(const bf16x8*)(Bsm + (wc * 64 + ni * 16 + lrow) * LDSP + quad * 8);
        #pragma unroll
        for (int mi = 0; mi < 4; ++mi)
            #pragma unroll
            for (int ni = 0; ni < 4; ++ni)
                acc[mi][ni] = __builtin_amdgcn_mfma_f32_16x16x32_bf16(
                    af[mi], bfr[ni], acc[mi][ni], 0, 0, 0);
    }
    #pragma unroll
    for (int mi = 0; mi < 4; ++mi) {
        #pragma unroll
        for (int ni = 0; ni < 4; ++ni) {
            int col = bn + wc * 64 + ni * 16 + lrow;
            float bv = bias[col];
            #pragma unroll
            for (int r = 0; r < 4; ++r) {
                int row = bm + wr * 64 + mi * 16 + quad * 4 + r;
                if (row < NMID) {
                    float v = acc[mi][ni][r] + bv;
                    h[(long long)row * DHID + col] = f2bf(fmaxf(v, 0.0f));
                }
            }
        }
    }
}

// p = h @ Wl2 (all rows); q = h @ Wr2 + b2 (rows < NTGT). WT2: 128 n-rows x 256 k.
__global__ __launch_bounds__(256) void gemm2_dual_mfma(
    const unsigned short* __restrict__ h, const unsigned short* __restrict__ WT2,
    const float* __restrict__ b2,
    float* __restrict__ p, float* __restrict__ qb)
{
    __shared__ unsigned short Asm[128 * LDSP];
    __shared__ unsigned short Bsm[128 * LDSP];
    const int tid = threadIdx.x;
    const int bm = blockIdx.x * 128;
    const int wave = tid >> 6, lane = tid & 63;
    const int lrow = lane & 15, quad = lane >> 4;
    const bool doq = (bm < NTGT);

    const int c0r = tid >> 2, c0s = tid & 3;
    const int c1r = (tid + 256) >> 2;
    int growA0 = bm + c0r; if (growA0 >= NMID) growA0 = NMID - 1;
    int growA1 = bm + c1r; if (growA1 >= NMID) growA1 = NMID - 1;

    uint4 pa0, pa1, pb0, pb1;
    auto gload = [&](int k0) {
        pa0 = *(const uint4*)(h + (long long)growA0 * DHID + k0 + c0s * 8);
        pa1 = *(const uint4*)(h + (long long)growA1 * DHID + k0 + c0s * 8);
        pb0 = *(const uint4*)(WT2 + (long long)c0r * 256 + k0 + c0s * 8);
        pb1 = *(const uint4*)(WT2 + (long long)c1r * 256 + k0 + c0s * 8);
    };

    f32x4 accP[2][4], accQ[2][4];
    #pragma unroll
    for (int i = 0; i < 2; ++i)
        #pragma unroll
        for (int j = 0; j < 4; ++j) {
            accP[i][j] = (f32x4){0.f, 0.f, 0.f, 0.f};
            accQ[i][j] = (f32x4){0.f, 0.f, 0.f, 0.f};
        }

    gload(0);
    for (int it = 0; it < 8; ++it) {
        if (it) __syncthreads();
        *(uint4*)(Asm + c0r * LDSP + c0s * 8) = pa0;
        *(uint4*)(Asm + c1r * LDSP + c0s * 8) = pa1;
        *(uint4*)(Bsm + c0r * LDSP + c0s * 8) = pb0;
        *(uint4*)(Bsm + c1r * LDSP + c0s * 8) = pb1;
        __syncthreads();
        if (it < 7) gload((it + 1) * 32);
        bf16x8 af[2], bp[4];
        #pragma unroll
        for (int mi = 0; mi < 2; ++mi)
            af[mi] = *(const bf16x8*)(Asm + (wave * 32 + mi * 16 + lrow) * LDSP + quad * 8);
        #pragma unroll
        for (int ni = 0; ni < 4; ++ni)
            bp[ni] = *(const bf16x8*)(Bsm + (ni * 16 + lrow) * LDSP + quad * 8);
        #pragma unroll
        for (int mi = 0; mi < 2; ++mi)
            #pragma unroll
            for (int ni = 0; ni < 4; ++ni)
                accP[mi][ni] = __builtin_amdgcn_mfma_f32_16x16x32_bf16(
                    af[mi], bp[ni], accP[mi][ni], 0, 0, 0);
        if (doq) {
            bf16x8 bq[4];
            #pragma unroll
            for (int ni = 0; ni < 4; ++ni)
                bq[ni] = *(const bf16x8*)(Bsm + (64 + ni * 16 + lrow) * LDSP + quad * 8);
            #pragma unroll
            for (int mi = 0; mi < 2; ++mi)
                #pragma unroll
                for (int ni = 0; ni < 4; ++ni)
                    accQ[mi][ni] = __builtin_amdgcn_mfma_f32_16x16x32_bf16(
                        af[mi], bq[ni], accQ[mi][ni], 0, 0, 0);
        }
    }
    #pragma unroll
    for (int mi = 0; mi < 2; ++mi) {
        #pragma unroll
        for (int ni = 0; ni < 4; ++ni) {
            int col = ni * 16 + lrow;
            #pragma unroll
            for (int r = 0; r < 4; ++r) {
                int row = bm + wave * 32 + mi * 16 + quad * 4 + r;
                if (row < NMID)
                    p[(long long)row * DOUT + col] = accP[mi][ni][r];
                if (doq && row < NTGT)
                    qb[(long long)row * DOUT + col] = accQ[mi][ni][r] + b2[col];
            }
        }
    }
}

extern "C" void kernel_launch(void* const* d_in, const int* in_sizes, int n_in,
                              void* d_out, int out_size, void* d_ws, size_t ws_size,
                              hipStream_t stream) {
    const float* x   = (const float*)d_in[0];
    const int*   ei1 = (const int*)d_in[1];
    const int*   ei2 = (const int*)d_in[2];
    const float* Wl1 = (const float*)d_in[3];
    const float* Wr1 = (const float*)d_in[4];
    const float* b1  = (const float*)d_in[5];
    const float* Wl2 = (const float*)d_in[6];
    const float* Wr2 = (const float*)d_in[7];
    const float* b2  = (const float*)d_in[8];
    float* out = (float*)d_out;

    unsigned short* xb    = (unsigned short*)d_ws;
    unsigned short* aggnb = xb + (size_t)NSRC * DIN;
    unsigned short* h     = aggnb + (size_t)NMID * DIN;
    unsigned short* WT1   = h + (size_t)NMID * DHID;
    unsigned short* WT2   = WT1 + 256 * 256;
    float* p    = (float*)(WT2 + 128 * 256);
    float* qb   = p + (size_t)NMID * DOUT;
    int* rs1    = (int*)(qb + (size_t)NTGT * DOUT);
    int* rs2    = rs1 + (NMID + 1);
    int* bhist1 = rs2 + (NTGT + 1);
    int* bhist2 = bhist1 + NBK1;
    int* bbase1 = bhist2 + NBK2;
    int* bbase2 = bbase1 + (NBK1 + 1);
    int* bcur1  = bbase2 + (NBK2 + 1);
    int* bcur2  = bcur1 + NBK1;
    int* csr1   = bcur2 + NBK2 + 1;
    int* csr2   = csr1 + NE1;
    uint2* gbuf1 = (uint2*)(((size_t)(csr2 + NE2) + 15) & ~(size_t)15);
    uint2* gbuf2 = gbuf1 + NE1;

    convert_all_kernel<<<(XCH + 65536 + 32768 + 255) / 256, 256, 0, stream>>>(
        x, Wl1, Wr1, Wl2, Wr2, xb, WT1, WT2);

    hipMemsetAsync(bhist1, 0, (size_t)(NBK1 + NBK2) * 4, stream);
    bucket_hist_kernel<<<NHC1 + NHC2, 256, 0, stream>>>(ei1, ei2, bhist1, bhist2);
    bucket_scan_kernel<<<1, 256, 0, stream>>>(bhist1, bhist2, bbase1, bbase2,
                                              bcur1, bcur2, rs1, rs2);
    bin_kernel<<<NCH1 + NCH2, 256, 0, stream>>>(ei1, ei2, bcur1, bcur2, gbuf1, gbuf2);
    bucket_csr_kernel<<<NBK1 + NBK2, 256, 0, stream>>>(
        gbuf1, gbuf2, bbase1, bbase2, rs1, rs2, csr1, csr2);

    gather1_kernel<<<(NMID + 3) / 4, 256, 0, stream>>>(xb, rs1, csr1, aggnb);
    {
        dim3 grid((NMID + 127) / 128, 2);
        gemm1_mfma<<<grid, 256, 0, stream>>>(aggnb, xb, WT1, b1, h);
    }
    gemm2_dual_mfma<<<(NMID + 127) / 128, 256, 0, stream>>>(h, WT2, b2, p, qb);
    gather2_final_kernel<<<(NTGT + 3) / 4, 256, 0, stream>>>(p, qb, rs2, csr2, out);
}